// Round 2
// baseline (3702.437 us; speedup 1.0000x reference)
//
#include <hip/hip_runtime.h>

// Problem constants (from reference).
constexpr int NN  = 50000;   // nodes
constexpr int NE  = 150000;  // edges
constexpr int IN  = 16;
constexpr int HID = 32;
constexpr int LAT = 16;
constexpr int EF  = 8;       // edge feature dim
constexpr int HE  = 128;     // edge-MLP hidden dim

// ---------------------------------------------------------------------------
// in-degree counts (float, for the mean normalization of c1/c2)
// ---------------------------------------------------------------------------
__global__ void count_kernel(const int* __restrict__ dst, float* __restrict__ cnt) {
  int e = blockIdx.x * blockDim.x + threadIdx.x;
  if (e < NE) atomicAdd(&cnt[dst[e]], 1.0f);
}

// ---------------------------------------------------------------------------
// Hot kernel, k-split: thread (e, kc) handles hidden units
// k in [kc*KCH, (kc+1)*KCH) and atomically accumulates its partial msg.
// NCHUNK=4 lifts wave supply from ~9/CU to ~37/CU (grid was the occupancy cap).
// w1/b1/w2 accesses are wave-uniform -> scalar loads (SGPR=112 confirmed).
// ---------------------------------------------------------------------------
template <int DIN, int DOUT, int NCHUNK>
__launch_bounds__(256)
__global__ void nnconv_edges(const float* __restrict__ xin,   // [NN, DIN]
                             const int*   __restrict__ src,   // [NE]
                             const int*   __restrict__ dst,   // [NE]
                             const float* __restrict__ ea,    // [NE, EF]
                             const float* __restrict__ w1,    // [EF, HE]
                             const float* __restrict__ b1,    // [HE]
                             const float* __restrict__ w2,    // [HE, DIN*DOUT]
                             const float* __restrict__ b2,    // [DIN*DOUT]
                             float* __restrict__ agg)         // [NN, DOUT]
{
  const int e = blockIdx.x * blockDim.x + threadIdx.x;
  if (e >= NE) return;
  constexpr int KCH = HE / NCHUNK;
  const int kc = blockIdx.y;           // wave-uniform chunk id
  const int k0 = kc * KCH;

  float eav[EF];
#pragma unroll
  for (int i = 0; i < EF; i++) eav[i] = ea[(long)e * EF + i];

  const int s = src[e];
  float xv[DIN];
#pragma unroll
  for (int i = 0; i < DIN; i++) xv[i] = xin[(long)s * DIN + i];

  float msg[DOUT];
#pragma unroll
  for (int o = 0; o < DOUT; o++) msg[o] = 0.0f;

#pragma unroll 1
  for (int k = k0; k < k0 + KCH; k++) {
    // h_k = relu(b1[k] + ea . w1[:,k])
    float hk = b1[k];
#pragma unroll
    for (int i = 0; i < EF; i++) hk = fmaf(eav[i], w1[i * HE + k], hk);
    hk = fmaxf(hk, 0.0f);

    const float* __restrict__ w2k = w2 + (long)k * (DIN * DOUT);
#pragma unroll
    for (int i = 0; i < DIN; i++) {
      const float xh = xv[i] * hk;
#pragma unroll
      for (int o = 0; o < DOUT; o++)
        msg[o] = fmaf(xh, w2k[i * DOUT + o], msg[o]);
    }
  }

  // b2 contribution once (chunk 0 only; branch is wave-uniform)
  if (kc == 0) {
#pragma unroll
    for (int i = 0; i < DIN; i++)
#pragma unroll
      for (int o = 0; o < DOUT; o++)
        msg[o] = fmaf(xv[i], b2[i * DOUT + o], msg[o]);
  }

  const int d = dst[e];
  const long base = (long)d * DOUT;
#pragma unroll
  for (int o = 0; o < DOUT; o++) atomicAdd(&agg[base + o], msg[o]);
}

// ---------------------------------------------------------------------------
// Epilogue: out = agg (/ max(cnt,1) if MEAN) + x@root + bias; optional relu.
// ---------------------------------------------------------------------------
template <int DIN, int DOUT, bool MEAN, bool RELU>
__launch_bounds__(256)
__global__ void finish_kernel(const float* __restrict__ agg,   // [NN, DOUT]
                              const float* __restrict__ cnt,   // [NN]
                              const float* __restrict__ xin,   // [NN, DIN]
                              const float* __restrict__ root,  // [DIN, DOUT]
                              const float* __restrict__ bias,  // [DOUT]
                              float* __restrict__ out)         // [NN, DOUT]
{
  const int n = blockIdx.x * blockDim.x + threadIdx.x;
  if (n >= NN) return;

  float xv[DIN];
#pragma unroll
  for (int i = 0; i < DIN; i++) xv[i] = xin[(long)n * DIN + i];

  const float inv = MEAN ? (1.0f / fmaxf(cnt[n], 1.0f)) : 1.0f;

#pragma unroll
  for (int o = 0; o < DOUT; o++) {
    float v = agg[(long)n * DOUT + o] * inv + bias[o];
#pragma unroll
    for (int i = 0; i < DIN; i++) v = fmaf(xv[i], root[i * DOUT + o], v);
    if (RELU) v = fmaxf(v, 0.0f);
    out[(long)n * DOUT + o] = v;
  }
}

// ---------------------------------------------------------------------------
extern "C" void kernel_launch(void* const* d_in, const int* in_sizes, int n_in,
                              void* d_out, int out_size, void* d_ws, size_t ws_size,
                              hipStream_t stream) {
  const float* x  = (const float*)d_in[0];
  const int*   ei = (const int*)d_in[1];
  const float* ea = (const float*)d_in[2];
  const int* src = ei;        // edge_index[0, :]
  const int* dst = ei + NE;   // edge_index[1, :]

  auto P = [&](int c, int j) -> const float* {
    return (const float*)d_in[3 + c * 6 + j];
  };

  float* ws  = (float*)d_ws;
  float* cnt = ws;                              // NN
  float* h1  = cnt + NN;                        // NN*HID
  float* h2  = h1 + (size_t)NN * HID;           // NN*HID
  float* agg = h2 + (size_t)NN * HID;           // NN*HID (reused per conv)

  float* out_mu = (float*)d_out;
  float* out_lv = out_mu + (size_t)NN * LAT;

  constexpr int NCHUNK = 4;
  const dim3 egrid((NE + 255) / 256, NCHUNK), eblk(256);
  const dim3 ngrid((NN + 255) / 256), nblk(256);

  // degree counts (same for all convs)
  hipMemsetAsync(cnt, 0, (size_t)NN * sizeof(float), stream);
  count_kernel<<<dim3((NE + 255) / 256), dim3(256), 0, stream>>>(dst, cnt);

  // conv1: 16 -> 32, mean, relu
  hipMemsetAsync(agg, 0, (size_t)NN * HID * sizeof(float), stream);
  nnconv_edges<IN, HID, NCHUNK><<<egrid, eblk, 0, stream>>>(
      x, src, dst, ea, P(0, 0), P(0, 1), P(0, 2), P(0, 3), agg);
  finish_kernel<IN, HID, true, true><<<ngrid, nblk, 0, stream>>>(
      agg, cnt, x, P(0, 4), P(0, 5), h1);

  // conv2: 32 -> 32, mean, relu
  hipMemsetAsync(agg, 0, (size_t)NN * HID * sizeof(float), stream);
  nnconv_edges<HID, HID, NCHUNK><<<egrid, eblk, 0, stream>>>(
      h1, src, dst, ea, P(1, 0), P(1, 1), P(1, 2), P(1, 3), agg);
  finish_kernel<HID, HID, true, true><<<ngrid, nblk, 0, stream>>>(
      agg, cnt, h1, P(1, 4), P(1, 5), h2);

  // cmu: 32 -> 16, no mean, no relu
  hipMemsetAsync(agg, 0, (size_t)NN * LAT * sizeof(float), stream);
  nnconv_edges<HID, LAT, NCHUNK><<<egrid, eblk, 0, stream>>>(
      h2, src, dst, ea, P(2, 0), P(2, 1), P(2, 2), P(2, 3), agg);
  finish_kernel<HID, LAT, false, false><<<ngrid, nblk, 0, stream>>>(
      agg, cnt, h2, P(2, 4), P(2, 5), out_mu);

  // clv: 32 -> 16, no mean, no relu
  hipMemsetAsync(agg, 0, (size_t)NN * LAT * sizeof(float), stream);
  nnconv_edges<HID, LAT, NCHUNK><<<egrid, eblk, 0, stream>>>(
      h2, src, dst, ea, P(3, 0), P(3, 1), P(3, 2), P(3, 3), agg);
  finish_kernel<HID, LAT, false, false><<<ngrid, nblk, 0, stream>>>(
      agg, cnt, h2, P(3, 4), P(3, 5), out_lv);
}

// Round 3
// 547.615 us; speedup vs baseline: 6.7610x; 6.7610x over previous
//
#include <hip/hip_runtime.h>

typedef __attribute__((ext_vector_type(8))) short short8;
typedef __attribute__((ext_vector_type(4))) float f32x4;

constexpr int NN  = 50000;
constexpr int NE  = 150000;
constexpr int IN  = 16;
constexpr int HID = 32;
constexpr int LAT = 16;
constexpr int EF  = 8;
constexpr int HE  = 128;
constexpr int NTILE = NE / 16;      // 9375 (exact)
constexpr int HSTR  = HE + 2;       // h LDS row stride (sentinel 1.0, 0.0)

// ---------------------------------------------------------------------------
// CSR build
// ---------------------------------------------------------------------------
__global__ void count_kernel(const int* __restrict__ dst, int* __restrict__ cnt) {
  int e = blockIdx.x * blockDim.x + threadIdx.x;
  if (e < NE) atomicAdd(&cnt[dst[e]], 1);
}

__launch_bounds__(1024)
__global__ void scan_kernel(const int* __restrict__ cnt, int* __restrict__ rowptr,
                            int* __restrict__ wptr) {
  __shared__ int part[1024];
  const int t = threadIdx.x;
  constexpr int CH = (NN + 1023) / 1024;  // 49
  const int base = t * CH;
  int s = 0;
  for (int j = 0; j < CH; j++) {
    int idx = base + j;
    if (idx < NN) s += cnt[idx];
  }
  part[t] = s;
  __syncthreads();
  for (int off = 1; off < 1024; off <<= 1) {
    int v = 0;
    if (t >= off) v = part[t - off];
    __syncthreads();
    part[t] += v;
    __syncthreads();
  }
  int run = part[t] - s;  // exclusive prefix
  for (int j = 0; j < CH; j++) {
    int idx = base + j;
    if (idx < NN) {
      rowptr[idx] = run;
      wptr[idx] = run;
      run += cnt[idx];
    }
  }
  if (t == 1023) rowptr[NN] = NE;
}

__global__ void fill_kernel(const int* __restrict__ dst, int* __restrict__ wptr,
                            int* __restrict__ eidx) {
  int e = blockIdx.x * blockDim.x + threadIdx.x;
  if (e < NE) {
    int pos = atomicAdd(&wptr[dst[e]], 1);
    eidx[pos] = e;
  }
}

// ---------------------------------------------------------------------------
// Weight swizzle: w2 fp32 [kk][i*DOUT+o] (+b2 as row HE, zeros row HE+1)
//  -> bf16 (RNE) layout [kk][o][i]  (B-fragment friendly: lane reads 8
//     contiguous i at fixed o,kk = one 16B load)
// ---------------------------------------------------------------------------
__global__ void swizzle_kernel(const float* __restrict__ w2, const float* __restrict__ b2,
                               unsigned short* __restrict__ w2b, int DIN_, int DOUT_) {
  int idx = blockIdx.x * blockDim.x + threadIdx.x;
  int tot = HSTR * DIN_ * DOUT_;
  if (idx >= tot) return;
  int i  = idx % DIN_;
  int o  = (idx / DIN_) % DOUT_;
  int kk = idx / (DIN_ * DOUT_);
  float v = 0.0f;
  if (kk < HE)       v = w2[(size_t)kk * DIN_ * DOUT_ + i * DOUT_ + o];
  else if (kk == HE) v = b2[i * DOUT_ + o];
  unsigned int u = __float_as_uint(v);
  u = (u + 0x7fffu + ((u >> 16) & 1u)) >> 16;  // RNE
  w2b[idx] = (unsigned short)u;
}

// ---------------------------------------------------------------------------
// MFMA edge kernel: block = 256 thr = 4 waves, 128 edges (8 A-tiles of 16).
// Phase 1: h = relu(ea@w1+b1) -> LDS bf16 [128][HSTR] (+ sentinels 1,0).
// Phase 2: per wave 2 A-tiles x OT out-tiles, K=(HE+pad)*DIN via
//          mfma_f32_16x16x32_bf16; A formed on the fly = x[src] (x) h.
// ---------------------------------------------------------------------------
template <int DIN, int DOUT>
__launch_bounds__(256)
__global__ void nnconv_mfma(const float* __restrict__ xin,   // [NN, DIN]
                            const int*   __restrict__ src,   // [NE]
                            const float* __restrict__ ea,    // [NE, EF]
                            const float* __restrict__ w1,    // [EF, HE]
                            const float* __restrict__ b1,    // [HE]
                            const unsigned short* __restrict__ w2b, // [HSTR][DOUT][DIN] bf16
                            float* __restrict__ msg)         // [NE, DOUT]
{
  constexpr int OT     = DOUT / 16;                   // out tiles (1 or 2)
  constexpr int STEPS  = (DIN == 32) ? (HE + 1) : (HE + 2) / 2;  // 129 or 65
  constexpr int KKSTEP = 32 / DIN;                    // kk advance per step
  constexpr int BSTRIDE = KKSTEP * DOUT * DIN;        // elements per step

  __shared__ float         ea_s[128 * EF];            // 4 KB
  __shared__ unsigned short h_s[128 * HSTR];          // 33.3 KB bf16

  const int tid = threadIdx.x;
  const int eb  = blockIdx.x * 128;

  // ---- stage ea (one float4 per thread) ----
  {
    int e = eb + (tid >> 1);
    float4 v = make_float4(0.f, 0.f, 0.f, 0.f);
    if (e < NE) v = *((const float4*)(ea + (size_t)e * EF) + (tid & 1));
    ((float4*)ea_s)[tid] = v;
  }
  __syncthreads();

  // ---- phase 1: h into LDS ----
  {
    const int kk = tid & 127;
    const int e0 = (tid >> 7) * 64;
    float w1r[EF];
#pragma unroll
    for (int i = 0; i < EF; i++) w1r[i] = w1[i * HE + kk];
    const float bk = b1[kk];
    for (int e = e0; e < e0 + 64; e++) {
      float hv = bk;
#pragma unroll
      for (int i = 0; i < EF; i++) hv = fmaf(ea_s[e * EF + i], w1r[i], hv);
      hv = fmaxf(hv, 0.0f);
      h_s[e * HSTR + kk] = (unsigned short)((__float_as_uint(hv) + 0x8000u) >> 16);
    }
    if (tid < 128) {                       // sentinels: h[e][HE]=1, h[e][HE+1]=0
      h_s[tid * HSTR + HE]     = 0x3F80;
      h_s[tid * HSTR + HE + 1] = 0;
    }
  }
  __syncthreads();

  // ---- phase 2: MFMA K-loop ----
  const int wave = tid >> 6;
  const int lane = tid & 63;
  const int m = lane & 15, q = lane >> 4;
  const int tg0 = blockIdx.x * 8 + wave * 2;          // first of 2 A-tiles

  const int i0 = (q * 8) % DIN;                       // lane's x slice start
  const int kq = (q * 8) / DIN;                       // lane's kk sub-offset

  // x fragments (fixed per lane for the whole K loop)
  float xv[2][8];
#pragma unroll
  for (int t2 = 0; t2 < 2; t2++) {
    const int tg = tg0 + t2;
    if (tg < NTILE) {
      const int s = src[tg * 16 + m];
      const float4* xp = (const float4*)(xin + (size_t)s * DIN + i0);
      float4 a = xp[0], b = xp[1];
      xv[t2][0] = a.x; xv[t2][1] = a.y; xv[t2][2] = a.z; xv[t2][3] = a.w;
      xv[t2][4] = b.x; xv[t2][5] = b.y; xv[t2][6] = b.z; xv[t2][7] = b.w;
    } else {
#pragma unroll
      for (int j = 0; j < 8; j++) xv[t2][j] = 0.f;
    }
  }

  f32x4 acc[2][OT];
#pragma unroll
  for (int t2 = 0; t2 < 2; t2++)
#pragma unroll
    for (int ot = 0; ot < OT; ot++) acc[t2][ot] = (f32x4){0.f, 0.f, 0.f, 0.f};

  // B base pointers (one per out-tile)
  const unsigned short* bp[OT];
#pragma unroll
  for (int ot = 0; ot < OT; ot++)
    bp[ot] = w2b + (size_t)(kq * DOUT + ot * 16 + m) * DIN + i0;

  const int hrow0 = wave * 32 + 0 * 16 + m;   // local LDS rows
  const int hrow1 = wave * 32 + 1 * 16 + m;

#pragma unroll 2
  for (int t = 0; t < STEPS; t++) {
    short8 bfr[OT];
#pragma unroll
    for (int ot = 0; ot < OT; ot++)
      bfr[ot] = *(const short8*)(bp[ot] + (size_t)t * BSTRIDE);

    const int kkidx = t * KKSTEP + kq;
#pragma unroll
    for (int t2 = 0; t2 < 2; t2++) {
      const int hrow = (t2 == 0) ? hrow0 : hrow1;
      const float hf =
          __uint_as_float(((unsigned int)h_s[hrow * HSTR + kkidx]) << 16);
      unsigned int u[4];
#pragma unroll
      for (int j = 0; j < 4; j++) {
        const float pl = xv[t2][2 * j]     * hf;
        const float ph = xv[t2][2 * j + 1] * hf;
        u[j] = __builtin_amdgcn_perm(__float_as_uint(ph), __float_as_uint(pl),
                                     0x07060302u);
      }
      union { unsigned int ui[4]; short8 s8; } cvt;
      cvt.ui[0] = u[0]; cvt.ui[1] = u[1]; cvt.ui[2] = u[2]; cvt.ui[3] = u[3];
#pragma unroll
      for (int ot = 0; ot < OT; ot++)
        acc[t2][ot] = __builtin_amdgcn_mfma_f32_16x16x32_bf16(
            cvt.s8, bfr[ot], acc[t2][ot], 0, 0, 0);
    }
  }

  // ---- store msg: D row = q*4+r (edge), col = m (out) ----
#pragma unroll
  for (int t2 = 0; t2 < 2; t2++) {
    const int tg = tg0 + t2;
    if (tg < NTILE) {
      const int ebase = tg * 16 + q * 4;
#pragma unroll
      for (int ot = 0; ot < OT; ot++)
#pragma unroll
        for (int r = 0; r < 4; r++)
          msg[(size_t)(ebase + r) * DOUT + ot * 16 + m] = acc[t2][ot][r];
    }
  }
}

// ---------------------------------------------------------------------------
// Finish: out[n] = (sum_{e in CSR(n)} msg[e]) (/deg if MEAN) + x@root + bias
// DOUT/4 threads per node, float4 per thread.
// ---------------------------------------------------------------------------
template <int DIN, int DOUT, bool MEAN, bool RELU>
__launch_bounds__(256)
__global__ void finish_kernel(const float* __restrict__ msg,
                              const int* __restrict__ rowptr,
                              const int* __restrict__ eidx,
                              const float* __restrict__ xin,
                              const float* __restrict__ root,
                              const float* __restrict__ bias,
                              float* __restrict__ out) {
  constexpr int TPN = DOUT / 4;
  const int gid = blockIdx.x * 256 + threadIdx.x;
  const int n = gid / TPN, sub = gid % TPN;
  if (n >= NN) return;
  const int o0 = sub * 4;

  const int r0 = rowptr[n], r1 = rowptr[n + 1];
  float ax = 0.f, ay = 0.f, az = 0.f, aw = 0.f;
  for (int idx = r0; idx < r1; idx++) {
    const int e = eidx[idx];
    const float4 mv = *(const float4*)(msg + (size_t)e * DOUT + o0);
    ax += mv.x; ay += mv.y; az += mv.z; aw += mv.w;
  }
  const float inv = MEAN ? 1.0f / fmaxf((float)(r1 - r0), 1.0f) : 1.0f;
  float vx = ax * inv + bias[o0 + 0];
  float vy = ay * inv + bias[o0 + 1];
  float vz = az * inv + bias[o0 + 2];
  float vw = aw * inv + bias[o0 + 3];
#pragma unroll
  for (int i = 0; i < DIN; i++) {
    const float xi = xin[(size_t)n * DIN + i];
    const float4 rv = *(const float4*)(root + (size_t)i * DOUT + o0);
    vx = fmaf(xi, rv.x, vx); vy = fmaf(xi, rv.y, vy);
    vz = fmaf(xi, rv.z, vz); vw = fmaf(xi, rv.w, vw);
  }
  if (RELU) {
    vx = fmaxf(vx, 0.f); vy = fmaxf(vy, 0.f);
    vz = fmaxf(vz, 0.f); vw = fmaxf(vw, 0.f);
  }
  float4 o = make_float4(vx, vy, vz, vw);
  *(float4*)(out + (size_t)n * DOUT + o0) = o;
}

// ---------------------------------------------------------------------------
extern "C" void kernel_launch(void* const* d_in, const int* in_sizes, int n_in,
                              void* d_out, int out_size, void* d_ws, size_t ws_size,
                              hipStream_t stream) {
  const float* x  = (const float*)d_in[0];
  const int*   ei = (const int*)d_in[1];
  const float* ea = (const float*)d_in[2];
  const int* src = ei;
  const int* dst = ei + NE;

  auto P = [&](int c, int j) -> const float* {
    return (const float*)d_in[3 + c * 6 + j];
  };

  // workspace layout (floats then ints then bf16 weights)
  float* h1  = (float*)d_ws;                       // NN*HID
  float* h2  = h1 + (size_t)NN * HID;              // NN*HID
  float* msg = h2 + (size_t)NN * HID;              // NE*32 (max DOUT)
  int* cnt    = (int*)(msg + (size_t)NE * 32);     // NN
  int* rowptr = cnt + NN;                          // NN+1 (pad to 50004)
  int* wptr   = rowptr + 50004;                    // NN+1 (pad)
  int* eidx   = wptr + 50004;                      // NE
  unsigned short* w2b_c1  = (unsigned short*)(eidx + NE);      // HSTR*32*16
  unsigned short* w2b_c2  = w2b_c1 + (size_t)HSTR * 32 * 16;   // HSTR*32*32
  unsigned short* w2b_mu  = w2b_c2 + (size_t)HSTR * 32 * 32;   // HSTR*16*32
  unsigned short* w2b_lv  = w2b_mu + (size_t)HSTR * 16 * 32;

  float* out_mu = (float*)d_out;
  float* out_lv = out_mu + (size_t)NN * LAT;

  // ---- CSR build ----
  hipMemsetAsync(cnt, 0, (size_t)NN * sizeof(int), stream);
  count_kernel<<<dim3((NE + 255) / 256), dim3(256), 0, stream>>>(dst, cnt);
  scan_kernel<<<dim3(1), dim3(1024), 0, stream>>>(cnt, rowptr, wptr);
  fill_kernel<<<dim3((NE + 255) / 256), dim3(256), 0, stream>>>(dst, wptr, eidx);

  // ---- weight swizzles ----
  {
    int t1 = HSTR * 16 * 32, t2 = HSTR * 32 * 32, t3 = HSTR * 32 * 16;
    swizzle_kernel<<<dim3((t1 + 255) / 256), dim3(256), 0, stream>>>(
        P(0, 2), P(0, 3), w2b_c1, IN, HID);
    swizzle_kernel<<<dim3((t2 + 255) / 256), dim3(256), 0, stream>>>(
        P(1, 2), P(1, 3), w2b_c2, HID, HID);
    swizzle_kernel<<<dim3((t3 + 255) / 256), dim3(256), 0, stream>>>(
        P(2, 2), P(2, 3), w2b_mu, HID, LAT);
    swizzle_kernel<<<dim3((t3 + 255) / 256), dim3(256), 0, stream>>>(
        P(3, 2), P(3, 3), w2b_lv, HID, LAT);
  }

  const dim3 egrid((NTILE + 7) / 8), eblk(256);

  // conv1: 16 -> 32, mean, relu
  nnconv_mfma<IN, HID><<<egrid, eblk, 0, stream>>>(
      x, src, ea, P(0, 0), P(0, 1), w2b_c1, msg);
  finish_kernel<IN, HID, true, true>
      <<<dim3((NN * (HID / 4) + 255) / 256), dim3(256), 0, stream>>>(
          msg, rowptr, eidx, x, P(0, 4), P(0, 5), h1);

  // conv2: 32 -> 32, mean, relu
  nnconv_mfma<HID, HID><<<egrid, eblk, 0, stream>>>(
      h1, src, ea, P(1, 0), P(1, 1), w2b_c2, msg);
  finish_kernel<HID, HID, true, true>
      <<<dim3((NN * (HID / 4) + 255) / 256), dim3(256), 0, stream>>>(
          msg, rowptr, eidx, h1, P(1, 4), P(1, 5), h2);

  // cmu: 32 -> 16
  nnconv_mfma<HID, LAT><<<egrid, eblk, 0, stream>>>(
      h2, src, ea, P(2, 0), P(2, 1), w2b_mu, msg);
  finish_kernel<HID, LAT, false, false>
      <<<dim3((NN * (LAT / 4) + 255) / 256), dim3(256), 0, stream>>>(
          msg, rowptr, eidx, h2, P(2, 4), P(2, 5), out_mu);

  // clv: 32 -> 16
  nnconv_mfma<HID, LAT><<<egrid, eblk, 0, stream>>>(
      h2, src, ea, P(3, 0), P(3, 1), w2b_lv, msg);
  finish_kernel<HID, LAT, false, false>
      <<<dim3((NN * (LAT / 4) + 255) / 256), dim3(256), 0, stream>>>(
          msg, rowptr, eidx, h2, P(3, 4), P(3, 5), out_lv);
}

// Round 4
// 433.677 us; speedup vs baseline: 8.5373x; 1.2627x over previous
//
#include <hip/hip_runtime.h>

typedef __attribute__((ext_vector_type(8))) short short8;
typedef __attribute__((ext_vector_type(4))) float f32x4;

constexpr int NN  = 50000;
constexpr int NE  = 150000;
constexpr int IN  = 16;
constexpr int HID = 32;
constexpr int LAT = 16;
constexpr int EF  = 8;
constexpr int HE  = 128;
constexpr int NTILE = NE / 16;      // 9375 (exact)
constexpr int HSTR  = HE + 2;       // h LDS row stride (sentinel 1.0, 0.0)

constexpr int SCB = 256;                    // scan block size
constexpr int NSB = (NN + SCB - 1) / SCB;   // 196 scan blocks (<= 256)

// ---------------------------------------------------------------------------
// CSR build
// ---------------------------------------------------------------------------
__global__ void count_kernel(const int* __restrict__ dst, int* __restrict__ cnt) {
  int e = blockIdx.x * blockDim.x + threadIdx.x;
  if (e < NE) atomicAdd(&cnt[dst[e]], 1);
}

// hierarchical scan: (1) per-block sums
__launch_bounds__(SCB)
__global__ void scan1(const int* __restrict__ cnt, int* __restrict__ bsum) {
  __shared__ int sdata[SCB];
  const int i = blockIdx.x * SCB + threadIdx.x;
  sdata[threadIdx.x] = (i < NN) ? cnt[i] : 0;
  __syncthreads();
  for (int off = SCB / 2; off > 0; off >>= 1) {
    if (threadIdx.x < off) sdata[threadIdx.x] += sdata[threadIdx.x + off];
    __syncthreads();
  }
  if (threadIdx.x == 0) bsum[blockIdx.x] = sdata[0];
}

// (2) exclusive scan of the block sums (one block, NSB<=256)
__launch_bounds__(SCB)
__global__ void scan2(int* __restrict__ bsum) {
  __shared__ int sdata[SCB];
  const int t = threadIdx.x;
  const int v = (t < NSB) ? bsum[t] : 0;
  sdata[t] = v;
  __syncthreads();
  for (int off = 1; off < SCB; off <<= 1) {
    int u = (t >= off) ? sdata[t - off] : 0;
    __syncthreads();
    sdata[t] += u;
    __syncthreads();
  }
  if (t < NSB) bsum[t] = sdata[t] - v;  // exclusive
}

// (3) per-block exclusive rescan + offset -> rowptr & wptr
__launch_bounds__(SCB)
__global__ void scan3(const int* __restrict__ cnt, const int* __restrict__ bsum,
                      int* __restrict__ rowptr, int* __restrict__ wptr) {
  __shared__ int sdata[SCB];
  const int i = blockIdx.x * SCB + threadIdx.x;
  const int t = threadIdx.x;
  const int v = (i < NN) ? cnt[i] : 0;
  sdata[t] = v;
  __syncthreads();
  for (int off = 1; off < SCB; off <<= 1) {
    int u = (t >= off) ? sdata[t - off] : 0;
    __syncthreads();
    sdata[t] += u;
    __syncthreads();
  }
  const int excl = sdata[t] - v + bsum[blockIdx.x];
  if (i < NN) {
    rowptr[i] = excl;
    wptr[i]   = excl;
  }
  if (i == NN - 1) rowptr[NN] = NE;
}

__global__ void fill_kernel(const int* __restrict__ dst, int* __restrict__ wptr,
                            int* __restrict__ eidx) {
  int e = blockIdx.x * blockDim.x + threadIdx.x;
  if (e < NE) {
    int pos = atomicAdd(&wptr[dst[e]], 1);
    eidx[pos] = e;
  }
}

// ---------------------------------------------------------------------------
// Weight swizzle: w2 fp32 [kk][i*DOUT+o] (+b2 as row HE, zeros row HE+1)
//  -> bf16 (RNE) layout [kk][o][i]
// ---------------------------------------------------------------------------
__global__ void swizzle_kernel(const float* __restrict__ w2, const float* __restrict__ b2,
                               unsigned short* __restrict__ w2b, int DIN_, int DOUT_) {
  int idx = blockIdx.x * blockDim.x + threadIdx.x;
  int tot = HSTR * DIN_ * DOUT_;
  if (idx >= tot) return;
  int i  = idx % DIN_;
  int o  = (idx / DIN_) % DOUT_;
  int kk = idx / (DIN_ * DOUT_);
  float v = 0.0f;
  if (kk < HE)       v = w2[(size_t)kk * DIN_ * DOUT_ + i * DOUT_ + o];
  else if (kk == HE) v = b2[i * DOUT_ + o];
  unsigned int u = __float_as_uint(v);
  u = (u + 0x7fffu + ((u >> 16) & 1u)) >> 16;  // RNE
  w2b[idx] = (unsigned short)u;
}

// ---------------------------------------------------------------------------
// MFMA edge kernel: block = 256 thr = 4 waves, 128 edges (8 A-tiles of 16).
// ---------------------------------------------------------------------------
template <int DIN, int DOUT>
__launch_bounds__(256)
__global__ void nnconv_mfma(const float* __restrict__ xin,   // [NN, DIN]
                            const int*   __restrict__ src,   // [NE]
                            const float* __restrict__ ea,    // [NE, EF]
                            const float* __restrict__ w1,    // [EF, HE]
                            const float* __restrict__ b1,    // [HE]
                            const unsigned short* __restrict__ w2b, // [HSTR][DOUT][DIN] bf16
                            float* __restrict__ msg)         // [NE, DOUT]
{
  constexpr int OT     = DOUT / 16;
  constexpr int STEPS  = (DIN == 32) ? (HE + 1) : (HE + 2) / 2;  // 129 or 65
  constexpr int KKSTEP = 32 / DIN;
  constexpr int BSTRIDE = KKSTEP * DOUT * DIN;

  __shared__ float         ea_s[128 * EF];
  __shared__ unsigned short h_s[128 * HSTR];

  const int tid = threadIdx.x;
  const int eb  = blockIdx.x * 128;

  // ---- stage ea ----
  {
    int e = eb + (tid >> 1);
    float4 v = make_float4(0.f, 0.f, 0.f, 0.f);
    if (e < NE) v = *((const float4*)(ea + (size_t)e * EF) + (tid & 1));
    ((float4*)ea_s)[tid] = v;
  }
  __syncthreads();

  // ---- phase 1: h into LDS ----
  {
    const int kk = tid & 127;
    const int e0 = (tid >> 7) * 64;
    float w1r[EF];
#pragma unroll
    for (int i = 0; i < EF; i++) w1r[i] = w1[i * HE + kk];
    const float bk = b1[kk];
    for (int e = e0; e < e0 + 64; e++) {
      float hv = bk;
#pragma unroll
      for (int i = 0; i < EF; i++) hv = fmaf(ea_s[e * EF + i], w1r[i], hv);
      hv = fmaxf(hv, 0.0f);
      h_s[e * HSTR + kk] = (unsigned short)((__float_as_uint(hv) + 0x8000u) >> 16);
    }
    if (tid < 128) {
      h_s[tid * HSTR + HE]     = 0x3F80;
      h_s[tid * HSTR + HE + 1] = 0;
    }
  }
  __syncthreads();

  // ---- phase 2: MFMA K-loop ----
  const int wave = tid >> 6;
  const int lane = tid & 63;
  const int m = lane & 15, q = lane >> 4;
  const int tg0 = blockIdx.x * 8 + wave * 2;

  const int i0 = (q * 8) % DIN;
  const int kq = (q * 8) / DIN;

  float xv[2][8];
#pragma unroll
  for (int t2 = 0; t2 < 2; t2++) {
    const int tg = tg0 + t2;
    if (tg < NTILE) {
      const int s = src[tg * 16 + m];
      const float4* xp = (const float4*)(xin + (size_t)s * DIN + i0);
      float4 a = xp[0], b = xp[1];
      xv[t2][0] = a.x; xv[t2][1] = a.y; xv[t2][2] = a.z; xv[t2][3] = a.w;
      xv[t2][4] = b.x; xv[t2][5] = b.y; xv[t2][6] = b.z; xv[t2][7] = b.w;
    } else {
#pragma unroll
      for (int j = 0; j < 8; j++) xv[t2][j] = 0.f;
    }
  }

  f32x4 acc[2][OT];
#pragma unroll
  for (int t2 = 0; t2 < 2; t2++)
#pragma unroll
    for (int ot = 0; ot < OT; ot++) acc[t2][ot] = (f32x4){0.f, 0.f, 0.f, 0.f};

  const unsigned short* bp[OT];
#pragma unroll
  for (int ot = 0; ot < OT; ot++)
    bp[ot] = w2b + (size_t)(kq * DOUT + ot * 16 + m) * DIN + i0;

  const int hrow0 = wave * 32 + 0 * 16 + m;
  const int hrow1 = wave * 32 + 1 * 16 + m;

#pragma unroll 2
  for (int t = 0; t < STEPS; t++) {
    short8 bfr[OT];
#pragma unroll
    for (int ot = 0; ot < OT; ot++)
      bfr[ot] = *(const short8*)(bp[ot] + (size_t)t * BSTRIDE);

    const int kkidx = t * KKSTEP + kq;
#pragma unroll
    for (int t2 = 0; t2 < 2; t2++) {
      const int hrow = (t2 == 0) ? hrow0 : hrow1;
      const float hf =
          __uint_as_float(((unsigned int)h_s[hrow * HSTR + kkidx]) << 16);
      unsigned int u[4];
#pragma unroll
      for (int j = 0; j < 4; j++) {
        const float pl = xv[t2][2 * j]     * hf;
        const float ph = xv[t2][2 * j + 1] * hf;
        u[j] = __builtin_amdgcn_perm(__float_as_uint(ph), __float_as_uint(pl),
                                     0x07060302u);
      }
      union { unsigned int ui[4]; short8 s8; } cvt;
      cvt.ui[0] = u[0]; cvt.ui[1] = u[1]; cvt.ui[2] = u[2]; cvt.ui[3] = u[3];
#pragma unroll
      for (int ot = 0; ot < OT; ot++)
        acc[t2][ot] = __builtin_amdgcn_mfma_f32_16x16x32_bf16(
            cvt.s8, bfr[ot], acc[t2][ot], 0, 0, 0);
    }
  }

  // ---- store msg ----
#pragma unroll
  for (int t2 = 0; t2 < 2; t2++) {
    const int tg = tg0 + t2;
    if (tg < NTILE) {
      const int ebase = tg * 16 + q * 4;
#pragma unroll
      for (int ot = 0; ot < OT; ot++)
#pragma unroll
        for (int r = 0; r < 4; r++)
          msg[(size_t)(ebase + r) * DOUT + ot * 16 + m] = acc[t2][ot][r];
    }
  }
}

// ---------------------------------------------------------------------------
// Finish: out[n] = (sum_{e in CSR(n)} msg[e]) (/deg if MEAN) + x@root + bias
// ---------------------------------------------------------------------------
template <int DIN, int DOUT, bool MEAN, bool RELU>
__launch_bounds__(256)
__global__ void finish_kernel(const float* __restrict__ msg,
                              const int* __restrict__ rowptr,
                              const int* __restrict__ eidx,
                              const float* __restrict__ xin,
                              const float* __restrict__ root,
                              const float* __restrict__ bias,
                              float* __restrict__ out) {
  constexpr int TPN = DOUT / 4;
  const int gid = blockIdx.x * 256 + threadIdx.x;
  const int n = gid / TPN, sub = gid % TPN;
  if (n >= NN) return;
  const int o0 = sub * 4;

  const int r0 = rowptr[n], r1 = rowptr[n + 1];
  float ax = 0.f, ay = 0.f, az = 0.f, aw = 0.f;
  for (int idx = r0; idx < r1; idx++) {
    const int e = eidx[idx];
    const float4 mv = *(const float4*)(msg + (size_t)e * DOUT + o0);
    ax += mv.x; ay += mv.y; az += mv.z; aw += mv.w;
  }
  const float inv = MEAN ? 1.0f / fmaxf((float)(r1 - r0), 1.0f) : 1.0f;
  float vx = ax * inv + bias[o0 + 0];
  float vy = ay * inv + bias[o0 + 1];
  float vz = az * inv + bias[o0 + 2];
  float vw = aw * inv + bias[o0 + 3];
#pragma unroll
  for (int i = 0; i < DIN; i++) {
    const float xi = xin[(size_t)n * DIN + i];
    const float4 rv = *(const float4*)(root + (size_t)i * DOUT + o0);
    vx = fmaf(xi, rv.x, vx); vy = fmaf(xi, rv.y, vy);
    vz = fmaf(xi, rv.z, vz); vw = fmaf(xi, rv.w, vw);
  }
  if (RELU) {
    vx = fmaxf(vx, 0.f); vy = fmaxf(vy, 0.f);
    vz = fmaxf(vz, 0.f); vw = fmaxf(vw, 0.f);
  }
  float4 o = make_float4(vx, vy, vz, vw);
  *(float4*)(out + (size_t)n * DOUT + o0) = o;
}

// ---------------------------------------------------------------------------
extern "C" void kernel_launch(void* const* d_in, const int* in_sizes, int n_in,
                              void* d_out, int out_size, void* d_ws, size_t ws_size,
                              hipStream_t stream) {
  const float* x  = (const float*)d_in[0];
  const int*   ei = (const int*)d_in[1];
  const float* ea = (const float*)d_in[2];
  const int* src = ei;
  const int* dst = ei + NE;

  auto P = [&](int c, int j) -> const float* {
    return (const float*)d_in[3 + c * 6 + j];
  };

  // workspace layout
  float* h1  = (float*)d_ws;                       // NN*HID
  float* h2  = h1 + (size_t)NN * HID;              // NN*HID
  float* msg = h2 + (size_t)NN * HID;              // NE*32 (max DOUT)
  int* cnt    = (int*)(msg + (size_t)NE * 32);     // NN
  int* rowptr = cnt + NN;                          // NN+1 (pad to 50004)
  int* wptr   = rowptr + 50004;                    // NN+1 (pad)
  int* eidx   = wptr + 50004;                      // NE
  int* bsum   = eidx + NE;                         // NSB (pad 256)
  unsigned short* w2b_c1  = (unsigned short*)(bsum + 256);     // HSTR*32*16
  unsigned short* w2b_c2  = w2b_c1 + (size_t)HSTR * 32 * 16;   // HSTR*32*32
  unsigned short* w2b_mu  = w2b_c2 + (size_t)HSTR * 32 * 32;   // HSTR*16*32
  unsigned short* w2b_lv  = w2b_mu + (size_t)HSTR * 16 * 32;

  float* out_mu = (float*)d_out;
  float* out_lv = out_mu + (size_t)NN * LAT;

  // ---- CSR build ----
  hipMemsetAsync(cnt, 0, (size_t)NN * sizeof(int), stream);
  count_kernel<<<dim3((NE + 255) / 256), dim3(256), 0, stream>>>(dst, cnt);
  scan1<<<dim3(NSB), dim3(SCB), 0, stream>>>(cnt, bsum);
  scan2<<<dim3(1), dim3(SCB), 0, stream>>>(bsum);
  scan3<<<dim3(NSB), dim3(SCB), 0, stream>>>(cnt, bsum, rowptr, wptr);
  fill_kernel<<<dim3((NE + 255) / 256), dim3(256), 0, stream>>>(dst, wptr, eidx);

  // ---- weight swizzles ----
  {
    int t1 = HSTR * 16 * 32, t2 = HSTR * 32 * 32, t3 = HSTR * 32 * 16;
    swizzle_kernel<<<dim3((t1 + 255) / 256), dim3(256), 0, stream>>>(
        P(0, 2), P(0, 3), w2b_c1, IN, HID);
    swizzle_kernel<<<dim3((t2 + 255) / 256), dim3(256), 0, stream>>>(
        P(1, 2), P(1, 3), w2b_c2, HID, HID);
    swizzle_kernel<<<dim3((t3 + 255) / 256), dim3(256), 0, stream>>>(
        P(2, 2), P(2, 3), w2b_mu, HID, LAT);
    swizzle_kernel<<<dim3((t3 + 255) / 256), dim3(256), 0, stream>>>(
        P(3, 2), P(3, 3), w2b_lv, HID, LAT);
  }

  const dim3 egrid((NTILE + 7) / 8), eblk(256);

  // conv1: 16 -> 32, mean, relu
  nnconv_mfma<IN, HID><<<egrid, eblk, 0, stream>>>(
      x, src, ea, P(0, 0), P(0, 1), w2b_c1, msg);
  finish_kernel<IN, HID, true, true>
      <<<dim3((NN * (HID / 4) + 255) / 256), dim3(256), 0, stream>>>(
          msg, rowptr, eidx, x, P(0, 4), P(0, 5), h1);

  // conv2: 32 -> 32, mean, relu
  nnconv_mfma<HID, HID><<<egrid, eblk, 0, stream>>>(
      h1, src, ea, P(1, 0), P(1, 1), w2b_c2, msg);
  finish_kernel<HID, HID, true, true>
      <<<dim3((NN * (HID / 4) + 255) / 256), dim3(256), 0, stream>>>(
          msg, rowptr, eidx, h1, P(1, 4), P(1, 5), h2);

  // cmu: 32 -> 16
  nnconv_mfma<HID, LAT><<<egrid, eblk, 0, stream>>>(
      h2, src, ea, P(2, 0), P(2, 1), w2b_mu, msg);
  finish_kernel<HID, LAT, false, false>
      <<<dim3((NN * (LAT / 4) + 255) / 256), dim3(256), 0, stream>>>(
          msg, rowptr, eidx, h2, P(2, 4), P(2, 5), out_mu);

  // clv: 32 -> 16
  nnconv_mfma<HID, LAT><<<egrid, eblk, 0, stream>>>(
      h2, src, ea, P(3, 0), P(3, 1), w2b_lv, msg);
  finish_kernel<HID, LAT, false, false>
      <<<dim3((NN * (LAT / 4) + 255) / 256), dim3(256), 0, stream>>>(
          msg, rowptr, eidx, h2, P(3, 4), P(3, 5), out_lv);
}

// Round 5
// 423.855 us; speedup vs baseline: 8.7351x; 1.0232x over previous
//
#include <hip/hip_runtime.h>

typedef __attribute__((ext_vector_type(8))) _Float16 half8;
typedef __attribute__((ext_vector_type(2))) _Float16 half2v;
typedef __attribute__((ext_vector_type(4))) float f32x4;

constexpr int NN  = 50000;
constexpr int NE  = 150000;
constexpr int IN  = 16;
constexpr int HID = 32;
constexpr int LAT = 16;
constexpr int EF  = 8;
constexpr int HE  = 128;
constexpr int NTILE = NE / 16;      // 9375 (exact)
constexpr int HSTR  = HE + 2;       // h LDS row stride (sentinel 1.0, 0.0)

constexpr int SCB = 256;                    // scan block size
constexpr int NSB = (NN + SCB - 1) / SCB;   // 196 scan blocks (<= 256)

// ---------------------------------------------------------------------------
// CSR build
// ---------------------------------------------------------------------------
__global__ void count_kernel(const int* __restrict__ dst, int* __restrict__ cnt) {
  int e = blockIdx.x * blockDim.x + threadIdx.x;
  if (e < NE) atomicAdd(&cnt[dst[e]], 1);
}

__launch_bounds__(SCB)
__global__ void scan1(const int* __restrict__ cnt, int* __restrict__ bsum) {
  __shared__ int sdata[SCB];
  const int i = blockIdx.x * SCB + threadIdx.x;
  sdata[threadIdx.x] = (i < NN) ? cnt[i] : 0;
  __syncthreads();
  for (int off = SCB / 2; off > 0; off >>= 1) {
    if (threadIdx.x < off) sdata[threadIdx.x] += sdata[threadIdx.x + off];
    __syncthreads();
  }
  if (threadIdx.x == 0) bsum[blockIdx.x] = sdata[0];
}

__launch_bounds__(SCB)
__global__ void scan2(int* __restrict__ bsum) {
  __shared__ int sdata[SCB];
  const int t = threadIdx.x;
  const int v = (t < NSB) ? bsum[t] : 0;
  sdata[t] = v;
  __syncthreads();
  for (int off = 1; off < SCB; off <<= 1) {
    int u = (t >= off) ? sdata[t - off] : 0;
    __syncthreads();
    sdata[t] += u;
    __syncthreads();
  }
  if (t < NSB) bsum[t] = sdata[t] - v;  // exclusive
}

__launch_bounds__(SCB)
__global__ void scan3(const int* __restrict__ cnt, const int* __restrict__ bsum,
                      int* __restrict__ rowptr, int* __restrict__ wptr) {
  __shared__ int sdata[SCB];
  const int i = blockIdx.x * SCB + threadIdx.x;
  const int t = threadIdx.x;
  const int v = (i < NN) ? cnt[i] : 0;
  sdata[t] = v;
  __syncthreads();
  for (int off = 1; off < SCB; off <<= 1) {
    int u = (t >= off) ? sdata[t - off] : 0;
    __syncthreads();
    sdata[t] += u;
    __syncthreads();
  }
  const int excl = sdata[t] - v + bsum[blockIdx.x];
  if (i < NN) {
    rowptr[i] = excl;
    wptr[i]   = excl;
  }
  if (i == NN - 1) rowptr[NN] = NE;
}

// epos[e] = CSR position of edge e (msg stored directly in CSR order)
__global__ void fill_kernel(const int* __restrict__ dst, int* __restrict__ wptr,
                            int* __restrict__ epos) {
  int e = blockIdx.x * blockDim.x + threadIdx.x;
  if (e < NE) epos[e] = atomicAdd(&wptr[dst[e]], 1);
}

// ---------------------------------------------------------------------------
// Weight swizzle: w2 fp32 [kk][i*DOUT+o] (+b2 as row HE, zeros row HE+1)
//  -> fp16 (RNE) layout [kk][o][i]
// ---------------------------------------------------------------------------
__global__ void swizzle_kernel(const float* __restrict__ w2, const float* __restrict__ b2,
                               _Float16* __restrict__ w2h, int DIN_, int DOUT_) {
  int idx = blockIdx.x * blockDim.x + threadIdx.x;
  int tot = HSTR * DIN_ * DOUT_;
  if (idx >= tot) return;
  int i  = idx % DIN_;
  int o  = (idx / DIN_) % DOUT_;
  int kk = idx / (DIN_ * DOUT_);
  float v = 0.0f;
  if (kk < HE)       v = w2[(size_t)kk * DIN_ * DOUT_ + i * DOUT_ + o];
  else if (kk == HE) v = b2[i * DOUT_ + o];
  w2h[idx] = (_Float16)v;
}

// ---------------------------------------------------------------------------
// MFMA edge kernel: block = 128 thr = 2 waves, 64 edges (4 A-tiles of 16).
// Phase 1: h = relu(ea@w1+b1) -> LDS fp16 [64][HSTR] (+ sentinels 1,0).
// Phase 2: per wave 2 A-tiles x OT out-tiles via mfma_f32_16x16x32_f16;
//          A = x[src] (x) h built with v_pk_mul_f16 (packed fp16).
// ---------------------------------------------------------------------------
template <int DIN, int DOUT>
__launch_bounds__(128)
__global__ void nnconv_mfma(const float* __restrict__ xin,   // [NN, DIN]
                            const int*   __restrict__ src,   // [NE]
                            const float* __restrict__ ea,    // [NE, EF]
                            const float* __restrict__ w1,    // [EF, HE]
                            const float* __restrict__ b1,    // [HE]
                            const _Float16* __restrict__ w2h, // [HSTR][DOUT][DIN] fp16
                            const int*   __restrict__ epos,  // [NE] CSR position
                            float* __restrict__ msg)         // [NE, DOUT] CSR-ordered
{
  constexpr int OT     = DOUT / 16;
  constexpr int STEPS  = (DIN == 32) ? (HE + 1) : (HE + 2) / 2;  // 129 or 65
  constexpr int KKSTEP = 32 / DIN;
  constexpr int BSTRIDE = KKSTEP * DOUT * DIN;

  __shared__ float    ea_s[64 * EF];       // 2 KB
  __shared__ _Float16 h_s[64 * HSTR];      // 16.6 KB

  const int tid = threadIdx.x;
  const int eb  = blockIdx.x * 64;

  // ---- stage ea (one float4 per thread) ----
  {
    int e = eb + (tid >> 1);
    float4 v = make_float4(0.f, 0.f, 0.f, 0.f);
    if (e < NE) v = *((const float4*)(ea + (size_t)e * EF) + (tid & 1));
    ((float4*)ea_s)[tid] = v;
  }
  __syncthreads();

  // ---- phase 1: h into LDS (thread = kk, loop over 64 edges) ----
  {
    const int kk = tid;
    float w1r[EF];
#pragma unroll
    for (int i = 0; i < EF; i++) w1r[i] = w1[i * HE + kk];
    const float bk = b1[kk];
#pragma unroll 4
    for (int e = 0; e < 64; e++) {
      float hv = bk;
#pragma unroll
      for (int i = 0; i < EF; i++) hv = fmaf(ea_s[e * EF + i], w1r[i], hv);
      hv = fmaxf(hv, 0.0f);
      h_s[e * HSTR + kk] = (_Float16)hv;
    }
    if (tid < 64) {                        // sentinels: h[e][HE]=1, h[e][HE+1]=0
      h_s[tid * HSTR + HE]     = (_Float16)1.0f;
      h_s[tid * HSTR + HE + 1] = (_Float16)0.0f;
    }
  }
  __syncthreads();

  // ---- phase 2: MFMA K-loop ----
  const int wave = tid >> 6;
  const int lane = tid & 63;
  const int m = lane & 15, q = lane >> 4;
  const int tg0 = blockIdx.x * 4 + wave * 2;          // first of 2 A-tiles

  const int i0 = (q * 8) % DIN;                       // lane's x slice start
  const int kq = (q * 8) / DIN;                       // lane's kk sub-offset

  // x fragments as packed fp16 pairs (fixed per lane)
  half2v xv[2][4];
#pragma unroll
  for (int t2 = 0; t2 < 2; t2++) {
    const int tg = tg0 + t2;
    if (tg < NTILE) {
      const int s = src[tg * 16 + m];
      const float4* xp = (const float4*)(xin + (size_t)s * DIN + i0);
      float4 a = xp[0], b = xp[1];
      xv[t2][0] = (half2v){(_Float16)a.x, (_Float16)a.y};
      xv[t2][1] = (half2v){(_Float16)a.z, (_Float16)a.w};
      xv[t2][2] = (half2v){(_Float16)b.x, (_Float16)b.y};
      xv[t2][3] = (half2v){(_Float16)b.z, (_Float16)b.w};
    } else {
#pragma unroll
      for (int j = 0; j < 4; j++) xv[t2][j] = (half2v){(_Float16)0.f, (_Float16)0.f};
    }
  }

  f32x4 acc[2][OT];
#pragma unroll
  for (int t2 = 0; t2 < 2; t2++)
#pragma unroll
    for (int ot = 0; ot < OT; ot++) acc[t2][ot] = (f32x4){0.f, 0.f, 0.f, 0.f};

  const _Float16* bp[OT];
#pragma unroll
  for (int ot = 0; ot < OT; ot++)
    bp[ot] = w2h + (size_t)(kq * DOUT + ot * 16 + m) * DIN + i0;

  const int hrow0 = wave * 32 + 0 * 16 + m;   // local LDS rows
  const int hrow1 = wave * 32 + 1 * 16 + m;

#pragma unroll 2
  for (int t = 0; t < STEPS; t++) {
    half8 bfr[OT];
#pragma unroll
    for (int ot = 0; ot < OT; ot++)
      bfr[ot] = *(const half8*)(bp[ot] + (size_t)t * BSTRIDE);

    const int kkidx = t * KKSTEP + kq;
#pragma unroll
    for (int t2 = 0; t2 < 2; t2++) {
      const int hrow = (t2 == 0) ? hrow0 : hrow1;
      const _Float16 hv = h_s[hrow * HSTR + kkidx];
      const half2v hb = (half2v){hv, hv};
      union { half2v h2[4]; half8 h8; } af;
#pragma unroll
      for (int j = 0; j < 4; j++) af.h2[j] = xv[t2][j] * hb;   // v_pk_mul_f16
#pragma unroll
      for (int ot = 0; ot < OT; ot++)
        acc[t2][ot] = __builtin_amdgcn_mfma_f32_16x16x32_f16(
            af.h8, bfr[ot], acc[t2][ot], 0, 0, 0);
    }
  }

  // ---- store msg in CSR order: row = q*4+r (edge), col = m (out) ----
#pragma unroll
  for (int t2 = 0; t2 < 2; t2++) {
    const int tg = tg0 + t2;
    if (tg < NTILE) {
      const int ebase = tg * 16 + q * 4;
      const int4 ep = *(const int4*)(epos + ebase);
      const int pr[4] = {ep.x, ep.y, ep.z, ep.w};
#pragma unroll
      for (int ot = 0; ot < OT; ot++)
#pragma unroll
        for (int r = 0; r < 4; r++)
          msg[(size_t)pr[r] * DOUT + ot * 16 + m] = acc[t2][ot][r];
    }
  }
}

// ---------------------------------------------------------------------------
// Finish: out[n] = (sum of contiguous CSR msg rows) (/deg if MEAN) + x@root + bias
// ---------------------------------------------------------------------------
template <int DIN, int DOUT, bool MEAN, bool RELU>
__launch_bounds__(256)
__global__ void finish_kernel(const float* __restrict__ msg,
                              const int* __restrict__ rowptr,
                              const float* __restrict__ xin,
                              const float* __restrict__ root,
                              const float* __restrict__ bias,
                              float* __restrict__ out) {
  constexpr int TPN = DOUT / 4;
  const int gid = blockIdx.x * 256 + threadIdx.x;
  const int n = gid / TPN, sub = gid % TPN;
  if (n >= NN) return;
  const int o0 = sub * 4;

  const int r0 = rowptr[n], r1 = rowptr[n + 1];
  float ax = 0.f, ay = 0.f, az = 0.f, aw = 0.f;
  for (int idx = r0; idx < r1; idx++) {
    const float4 mv = *(const float4*)(msg + (size_t)idx * DOUT + o0);
    ax += mv.x; ay += mv.y; az += mv.z; aw += mv.w;
  }
  const float inv = MEAN ? 1.0f / fmaxf((float)(r1 - r0), 1.0f) : 1.0f;
  float vx = ax * inv + bias[o0 + 0];
  float vy = ay * inv + bias[o0 + 1];
  float vz = az * inv + bias[o0 + 2];
  float vw = aw * inv + bias[o0 + 3];
#pragma unroll
  for (int i = 0; i < DIN; i++) {
    const float xi = xin[(size_t)n * DIN + i];
    const float4 rv = *(const float4*)(root + (size_t)i * DOUT + o0);
    vx = fmaf(xi, rv.x, vx); vy = fmaf(xi, rv.y, vy);
    vz = fmaf(xi, rv.z, vz); vw = fmaf(xi, rv.w, vw);
  }
  if (RELU) {
    vx = fmaxf(vx, 0.f); vy = fmaxf(vy, 0.f);
    vz = fmaxf(vz, 0.f); vw = fmaxf(vw, 0.f);
  }
  float4 o = make_float4(vx, vy, vz, vw);
  *(float4*)(out + (size_t)n * DOUT + o0) = o;
}

// ---------------------------------------------------------------------------
extern "C" void kernel_launch(void* const* d_in, const int* in_sizes, int n_in,
                              void* d_out, int out_size, void* d_ws, size_t ws_size,
                              hipStream_t stream) {
  const float* x  = (const float*)d_in[0];
  const int*   ei = (const int*)d_in[1];
  const float* ea = (const float*)d_in[2];
  const int* src = ei;
  const int* dst = ei + NE;

  auto P = [&](int c, int j) -> const float* {
    return (const float*)d_in[3 + c * 6 + j];
  };

  // workspace layout
  float* h1  = (float*)d_ws;                       // NN*HID
  float* h2  = h1 + (size_t)NN * HID;              // NN*HID
  float* msg = h2 + (size_t)NN * HID;              // NE*32 (max DOUT)
  int* cnt    = (int*)(msg + (size_t)NE * 32);     // NN
  int* rowptr = cnt + NN;                          // NN+1 (pad to 50004)
  int* wptr   = rowptr + 50004;                    // NN+1 (pad)
  int* epos   = wptr + 50004;                      // NE
  int* bsum   = epos + NE;                         // NSB (pad 256)
  _Float16* w2h_c1 = (_Float16*)(bsum + 256);          // HSTR*32*16
  _Float16* w2h_c2 = w2h_c1 + (size_t)HSTR * 32 * 16;  // HSTR*32*32
  _Float16* w2h_mu = w2h_c2 + (size_t)HSTR * 32 * 32;  // HSTR*16*32
  _Float16* w2h_lv = w2h_mu + (size_t)HSTR * 16 * 32;

  float* out_mu = (float*)d_out;
  float* out_lv = out_mu + (size_t)NN * LAT;

  // ---- CSR build ----
  hipMemsetAsync(cnt, 0, (size_t)NN * sizeof(int), stream);
  count_kernel<<<dim3((NE + 255) / 256), dim3(256), 0, stream>>>(dst, cnt);
  scan1<<<dim3(NSB), dim3(SCB), 0, stream>>>(cnt, bsum);
  scan2<<<dim3(1), dim3(SCB), 0, stream>>>(bsum);
  scan3<<<dim3(NSB), dim3(SCB), 0, stream>>>(cnt, bsum, rowptr, wptr);
  fill_kernel<<<dim3((NE + 255) / 256), dim3(256), 0, stream>>>(dst, wptr, epos);

  // ---- weight swizzles ----
  {
    int t1 = HSTR * 16 * 32, t2 = HSTR * 32 * 32, t3 = HSTR * 32 * 16;
    swizzle_kernel<<<dim3((t1 + 255) / 256), dim3(256), 0, stream>>>(
        P(0, 2), P(0, 3), w2h_c1, IN, HID);
    swizzle_kernel<<<dim3((t2 + 255) / 256), dim3(256), 0, stream>>>(
        P(1, 2), P(1, 3), w2h_c2, HID, HID);
    swizzle_kernel<<<dim3((t3 + 255) / 256), dim3(256), 0, stream>>>(
        P(2, 2), P(2, 3), w2h_mu, HID, LAT);
    swizzle_kernel<<<dim3((t3 + 255) / 256), dim3(256), 0, stream>>>(
        P(3, 2), P(3, 3), w2h_lv, HID, LAT);
  }

  const dim3 egrid((NTILE + 3) / 4), eblk(128);   // 64 edges / block, 2 waves

  // conv1: 16 -> 32, mean, relu
  nnconv_mfma<IN, HID><<<egrid, eblk, 0, stream>>>(
      x, src, ea, P(0, 0), P(0, 1), w2h_c1, epos, msg);
  finish_kernel<IN, HID, true, true>
      <<<dim3((NN * (HID / 4) + 255) / 256), dim3(256), 0, stream>>>(
          msg, rowptr, x, P(0, 4), P(0, 5), h1);

  // conv2: 32 -> 32, mean, relu
  nnconv_mfma<HID, HID><<<egrid, eblk, 0, stream>>>(
      h1, src, ea, P(1, 0), P(1, 1), w2h_c2, epos, msg);
  finish_kernel<HID, HID, true, true>
      <<<dim3((NN * (HID / 4) + 255) / 256), dim3(256), 0, stream>>>(
          msg, rowptr, h1, P(1, 4), P(1, 5), h2);

  // cmu: 32 -> 16
  nnconv_mfma<HID, LAT><<<egrid, eblk, 0, stream>>>(
      h2, src, ea, P(2, 0), P(2, 1), w2h_mu, epos, msg);
  finish_kernel<HID, LAT, false, false>
      <<<dim3((NN * (LAT / 4) + 255) / 256), dim3(256), 0, stream>>>(
          msg, rowptr, h2, P(2, 4), P(2, 5), out_mu);

  // clv: 32 -> 16
  nnconv_mfma<HID, LAT><<<egrid, eblk, 0, stream>>>(
      h2, src, ea, P(3, 0), P(3, 1), w2h_lv, epos, msg);
  finish_kernel<HID, LAT, false, false>
      <<<dim3((NN * (LAT / 4) + 255) / 256), dim3(256), 0, stream>>>(
          msg, rowptr, h2, P(3, 4), P(3, 5), out_lv);
}

// Round 8
// 401.084 us; speedup vs baseline: 9.2311x; 1.0568x over previous
//
#include <hip/hip_runtime.h>

typedef __attribute__((ext_vector_type(8))) _Float16 half8;
typedef __attribute__((ext_vector_type(4))) _Float16 half4v;
typedef __attribute__((ext_vector_type(2))) _Float16 half2v;
typedef __attribute__((ext_vector_type(4))) float f32x4;

constexpr int NN  = 50000;
constexpr int NE  = 150000;
constexpr int IN  = 16;
constexpr int HID = 32;
constexpr int LAT = 16;
constexpr int EF  = 8;
constexpr int HE  = 128;
constexpr int NTILE = NE / 16;      // 9375 (exact)
constexpr int HSTR  = HE + 2;       // h LDS row stride (sentinels: 1.0, 0.0)

constexpr int SCB = 256;
constexpr int NSB = (NN + SCB - 1) / SCB;   // 196

// ---------------------------------------------------------------------------
// CSR build (verified rounds 4-7)
// ---------------------------------------------------------------------------
__global__ void count_kernel(const int* __restrict__ dst, int* __restrict__ cnt) {
  int e = blockIdx.x * blockDim.x + threadIdx.x;
  if (e < NE) atomicAdd(&cnt[dst[e]], 1);
}

__launch_bounds__(SCB)
__global__ void scan1(const int* __restrict__ cnt, int* __restrict__ bsum) {
  __shared__ int sdata[SCB];
  const int i = blockIdx.x * SCB + threadIdx.x;
  sdata[threadIdx.x] = (i < NN) ? cnt[i] : 0;
  __syncthreads();
  for (int off = SCB / 2; off > 0; off >>= 1) {
    if (threadIdx.x < off) sdata[threadIdx.x] += sdata[threadIdx.x + off];
    __syncthreads();
  }
  if (threadIdx.x == 0) bsum[blockIdx.x] = sdata[0];
}

__launch_bounds__(SCB)
__global__ void scan2(int* __restrict__ bsum) {
  __shared__ int sdata[SCB];
  const int t = threadIdx.x;
  const int v = (t < NSB) ? bsum[t] : 0;
  sdata[t] = v;
  __syncthreads();
  for (int off = 1; off < SCB; off <<= 1) {
    int u = (t >= off) ? sdata[t - off] : 0;
    __syncthreads();
    sdata[t] += u;
    __syncthreads();
  }
  if (t < NSB) bsum[t] = sdata[t] - v;  // exclusive
}

__launch_bounds__(SCB)
__global__ void scan3(const int* __restrict__ cnt, const int* __restrict__ bsum,
                      int* __restrict__ rowptr, int* __restrict__ wptr) {
  __shared__ int sdata[SCB];
  const int i = blockIdx.x * SCB + threadIdx.x;
  const int t = threadIdx.x;
  const int v = (i < NN) ? cnt[i] : 0;
  sdata[t] = v;
  __syncthreads();
  for (int off = 1; off < SCB; off <<= 1) {
    int u = (t >= off) ? sdata[t - off] : 0;
    __syncthreads();
    sdata[t] += u;
    __syncthreads();
  }
  const int excl = sdata[t] - v + bsum[blockIdx.x];
  if (i < NN) {
    rowptr[i] = excl;
    wptr[i]   = excl;
  }
  if (i == NN - 1) rowptr[NN] = NE;
}

__global__ void fill_kernel(const int* __restrict__ dst, int* __restrict__ wptr,
                            int* __restrict__ epos) {
  int e = blockIdx.x * blockDim.x + threadIdx.x;
  if (e < NE) epos[e] = atomicAdd(&wptr[dst[e]], 1);
}

// ---------------------------------------------------------------------------
// Weight swizzle (verified round 5): fp32 w2[kk][i*DOUT+o] (+b2 at kk=HE,
// zeros at kk=HE+1) -> fp16 layout [kk][o][i], kk in [0, HSTR)
// ---------------------------------------------------------------------------
__global__ void swizzle_kernel(const float* __restrict__ w2, const float* __restrict__ b2,
                               _Float16* __restrict__ w2h, int DIN_, int DOUT_) {
  int idx = blockIdx.x * blockDim.x + threadIdx.x;
  int tot = HSTR * DIN_ * DOUT_;
  if (idx >= tot) return;
  int i  = idx % DIN_;
  int o  = (idx / DIN_) % DOUT_;
  int kk = idx / (DIN_ * DOUT_);
  float v = 0.0f;
  if (kk < HE)       v = w2[(size_t)kk * DIN_ * DOUT_ + i * DOUT_ + o];
  else if (kk == HE) v = b2[i * DOUT_ + o];
  w2h[idx] = (_Float16)v;
}

// ---------------------------------------------------------------------------
// MFMA edge kernel. Block = 128 thr = 2 waves = 64 edges (4 A-tiles of 16).
// Non-dual: one edge-MLP, DOUT=32 (two out-tiles) — round-5/7 verified.
// DUAL (cmu+clv): each conv has ITS OWN edge-MLP (w1/b1) — run two
// sequential passes, rebuilding h in LDS between them; share ea staging,
// x-fragments, and epos/store addressing.
// ---------------------------------------------------------------------------
template <int DIN, int DOUT, bool DUAL>
__launch_bounds__(128)
__global__ void nnconv_mfma(const float* __restrict__ xin,
                            const int*   __restrict__ src,
                            const float* __restrict__ ea,
                            const float* __restrict__ w1A,
                            const float* __restrict__ b1A,
                            const float* __restrict__ w1B,   // DUAL only
                            const float* __restrict__ b1B,   // DUAL only
                            const _Float16* __restrict__ w2hA, // [HSTR][DOUT][DIN]
                            const _Float16* __restrict__ w2hB, // DUAL only
                            const int*   __restrict__ epos,
                            _Float16* __restrict__ msgA,       // CSR-ordered fp16
                            _Float16* __restrict__ msgB)       // DUAL only
{
  constexpr int STEPS   = (DIN == 32) ? (HE + 1) : (HE + 2) / 2;  // 129 / 65
  constexpr int KKSTEP  = 32 / DIN;
  constexpr int BSTRIDE = KKSTEP * DOUT * DIN;

  __shared__ float    ea_s[64 * EF];       // 2 KB
  __shared__ _Float16 h_s[64 * HSTR];      // 16.6 KB

  const int tid = threadIdx.x;
  const int eb  = blockIdx.x * 64;

  // ---- stage ea ----
  {
    int e = eb + (tid >> 1);
    float4 v = make_float4(0.f, 0.f, 0.f, 0.f);
    if (e < NE) v = *((const float4*)(ea + (size_t)e * EF) + (tid & 1));
    ((float4*)ea_s)[tid] = v;
  }
  __syncthreads();

  // ---- phase 1 builder: h = relu(ea@w1+b1) into LDS (thread = kk) ----
  auto build_h = [&](const float* __restrict__ w1, const float* __restrict__ b1) {
    const int kk = tid;
    float w1r[EF];
#pragma unroll
    for (int i = 0; i < EF; i++) w1r[i] = w1[i * HE + kk];
    const float bk = b1[kk];
#pragma unroll 4
    for (int e = 0; e < 64; e++) {
      float hv = bk;
#pragma unroll
      for (int i = 0; i < EF; i++) hv = fmaf(ea_s[e * EF + i], w1r[i], hv);
      hv = fmaxf(hv, 0.0f);
      h_s[e * HSTR + kk] = (_Float16)hv;
    }
    if (tid < 64) {                        // sentinels: h[e][HE]=1, h[e][HE+1]=0
      h_s[tid * HSTR + HE]     = (_Float16)1.0f;
      h_s[tid * HSTR + HE + 1] = (_Float16)0.0f;
    }
  };

  build_h(w1A, b1A);
  __syncthreads();

  // ---- phase 2 common setup ----
  const int wave = tid >> 6;
  const int lane = tid & 63;
  const int m = lane & 15, q = lane >> 4;
  const int tg0 = blockIdx.x * 4 + wave * 2;

  const int i0 = (q * 8) % DIN;
  const int kq = (q * 8) / DIN;

  half2v xv[2][4];
#pragma unroll
  for (int t2 = 0; t2 < 2; t2++) {
    const int tg = tg0 + t2;
    if (tg < NTILE) {
      const int s = src[tg * 16 + m];
      const float4* xp = (const float4*)(xin + (size_t)s * DIN + i0);
      float4 a = xp[0], b = xp[1];
      xv[t2][0] = (half2v){(_Float16)a.x, (_Float16)a.y};
      xv[t2][1] = (half2v){(_Float16)a.z, (_Float16)a.w};
      xv[t2][2] = (half2v){(_Float16)b.x, (_Float16)b.y};
      xv[t2][3] = (half2v){(_Float16)b.z, (_Float16)b.w};
    } else {
#pragma unroll
      for (int j = 0; j < 4; j++) xv[t2][j] = (half2v){(_Float16)0.f, (_Float16)0.f};
    }
  }

  f32x4 acc[2][2];
#pragma unroll
  for (int t2 = 0; t2 < 2; t2++)
#pragma unroll
    for (int f = 0; f < 2; f++) acc[t2][f] = (f32x4){0.f, 0.f, 0.f, 0.f};

  const int hrow0 = wave * 32 + m;
  const int hrow1 = wave * 32 + 16 + m;

  if constexpr (DUAL) {
    // ---- pass 1: mu (h already = h_mu) ----
    {
      const _Float16* bp = w2hA + (size_t)(kq * DOUT + m) * DIN + i0;
#pragma unroll 4
      for (int t = 0; t < STEPS; t++) {
        const half8 bfr = *(const half8*)(bp + (size_t)t * BSTRIDE);
        const int kkidx = t * KKSTEP + kq;
#pragma unroll
        for (int t2 = 0; t2 < 2; t2++) {
          const int hrow = (t2 == 0) ? hrow0 : hrow1;
          const _Float16 hv = h_s[hrow * HSTR + kkidx];
          const half2v hb = (half2v){hv, hv};
          union { half2v h2[4]; half8 h8; } af;
#pragma unroll
          for (int j = 0; j < 4; j++) af.h2[j] = xv[t2][j] * hb;
          acc[t2][0] = __builtin_amdgcn_mfma_f32_16x16x32_f16(af.h8, bfr,
                                                              acc[t2][0], 0, 0, 0);
        }
      }
    }
    // ---- rebuild h for lv (own edge-MLP!), then pass 2 ----
    __syncthreads();               // all waves done reading h_mu
    build_h(w1B, b1B);
    __syncthreads();
    {
      const _Float16* bp = w2hB + (size_t)(kq * DOUT + m) * DIN + i0;
#pragma unroll 4
      for (int t = 0; t < STEPS; t++) {
        const half8 bfr = *(const half8*)(bp + (size_t)t * BSTRIDE);
        const int kkidx = t * KKSTEP + kq;
#pragma unroll
        for (int t2 = 0; t2 < 2; t2++) {
          const int hrow = (t2 == 0) ? hrow0 : hrow1;
          const _Float16 hv = h_s[hrow * HSTR + kkidx];
          const half2v hb = (half2v){hv, hv};
          union { half2v h2[4]; half8 h8; } af;
#pragma unroll
          for (int j = 0; j < 4; j++) af.h2[j] = xv[t2][j] * hb;
          acc[t2][1] = __builtin_amdgcn_mfma_f32_16x16x32_f16(af.h8, bfr,
                                                              acc[t2][1], 0, 0, 0);
        }
      }
    }
  } else {
    // ---- round-5/7 verified: one h, two out-tiles ----
    const _Float16* bp0 = w2hA + (size_t)(kq * DOUT + 0 + m) * DIN + i0;
    const _Float16* bp1 = w2hA + (size_t)(kq * DOUT + 16 + m) * DIN + i0;
#pragma unroll 4
    for (int t = 0; t < STEPS; t++) {
      const half8 bfr0 = *(const half8*)(bp0 + (size_t)t * BSTRIDE);
      const half8 bfr1 = *(const half8*)(bp1 + (size_t)t * BSTRIDE);
      const int kkidx = t * KKSTEP + kq;
#pragma unroll
      for (int t2 = 0; t2 < 2; t2++) {
        const int hrow = (t2 == 0) ? hrow0 : hrow1;
        const _Float16 hv = h_s[hrow * HSTR + kkidx];
        const half2v hb = (half2v){hv, hv};
        union { half2v h2[4]; half8 h8; } af;
#pragma unroll
        for (int j = 0; j < 4; j++) af.h2[j] = xv[t2][j] * hb;
        acc[t2][0] = __builtin_amdgcn_mfma_f32_16x16x32_f16(af.h8, bfr0,
                                                            acc[t2][0], 0, 0, 0);
        acc[t2][1] = __builtin_amdgcn_mfma_f32_16x16x32_f16(af.h8, bfr1,
                                                            acc[t2][1], 0, 0, 0);
      }
    }
  }

  // ---- store msg (fp16) in CSR order: D row = q*4+r (edge), col = m ----
#pragma unroll
  for (int t2 = 0; t2 < 2; t2++) {
    const int tg = tg0 + t2;
    if (tg < NTILE) {
      const int ebase = tg * 16 + q * 4;
      const int4 ep = *(const int4*)(epos + ebase);
      const int pr[4] = {ep.x, ep.y, ep.z, ep.w};
      if (DUAL) {
#pragma unroll
        for (int r = 0; r < 4; r++) {
          msgA[(size_t)pr[r] * DOUT + m] = (_Float16)acc[t2][0][r];
          msgB[(size_t)pr[r] * DOUT + m] = (_Float16)acc[t2][1][r];
        }
      } else {
#pragma unroll
        for (int f = 0; f < 2; f++)
#pragma unroll
          for (int r = 0; r < 4; r++)
            msgA[(size_t)pr[r] * DOUT + f * 16 + m] = (_Float16)acc[t2][f][r];
      }
    }
  }
}

// ---------------------------------------------------------------------------
// Finish (single): out = (CSR-sum of fp16 msg) /deg? + x@root + bias, relu?
// ---------------------------------------------------------------------------
template <int DIN, int DOUT, bool MEAN, bool RELU>
__launch_bounds__(256)
__global__ void finish_kernel(const _Float16* __restrict__ msg,
                              const int* __restrict__ rowptr,
                              const float* __restrict__ xin,
                              const float* __restrict__ root,
                              const float* __restrict__ bias,
                              float* __restrict__ out) {
  constexpr int TPN = DOUT / 4;
  const int gid = blockIdx.x * 256 + threadIdx.x;
  const int n = gid / TPN, sub = gid % TPN;
  if (n >= NN) return;
  const int o0 = sub * 4;

  const int r0 = rowptr[n], r1 = rowptr[n + 1];
  float ax = 0.f, ay = 0.f, az = 0.f, aw = 0.f;
  for (int idx = r0; idx < r1; idx++) {
    const half4v mv = *(const half4v*)(msg + (size_t)idx * DOUT + o0);
    ax += (float)mv.x; ay += (float)mv.y; az += (float)mv.z; aw += (float)mv.w;
  }
  const float inv = MEAN ? 1.0f / fmaxf((float)(r1 - r0), 1.0f) : 1.0f;
  float vx = ax * inv + bias[o0 + 0];
  float vy = ay * inv + bias[o0 + 1];
  float vz = az * inv + bias[o0 + 2];
  float vw = aw * inv + bias[o0 + 3];
#pragma unroll
  for (int i = 0; i < DIN; i++) {
    const float xi = xin[(size_t)n * DIN + i];
    const float4 rv = *(const float4*)(root + (size_t)i * DOUT + o0);
    vx = fmaf(xi, rv.x, vx); vy = fmaf(xi, rv.y, vy);
    vz = fmaf(xi, rv.z, vz); vw = fmaf(xi, rv.w, vw);
  }
  if (RELU) {
    vx = fmaxf(vx, 0.f); vy = fmaxf(vy, 0.f);
    vz = fmaxf(vz, 0.f); vw = fmaxf(vw, 0.f);
  }
  *(float4*)(out + (size_t)n * DOUT + o0) = make_float4(vx, vy, vz, vw);
}

// Fused finish for mu+lv (DOUT=LAT=16, no mean, no relu)
template <int DIN>
__launch_bounds__(256)
__global__ void finish_dual(const _Float16* __restrict__ msgA,
                            const _Float16* __restrict__ msgB,
                            const int* __restrict__ rowptr,
                            const float* __restrict__ xin,
                            const float* __restrict__ rootA,
                            const float* __restrict__ biasA,
                            const float* __restrict__ rootB,
                            const float* __restrict__ biasB,
                            float* __restrict__ outA,
                            float* __restrict__ outB) {
  constexpr int TPN = LAT / 4;
  const int gid = blockIdx.x * 256 + threadIdx.x;
  const int n = gid / TPN, sub = gid % TPN;
  if (n >= NN) return;
  const int o0 = sub * 4;

  const int r0 = rowptr[n], r1 = rowptr[n + 1];
  float a0 = 0.f, a1 = 0.f, a2 = 0.f, a3 = 0.f;
  float b0 = 0.f, b1 = 0.f, b2 = 0.f, b3 = 0.f;
  for (int idx = r0; idx < r1; idx++) {
    const half4v ma = *(const half4v*)(msgA + (size_t)idx * LAT + o0);
    const half4v mb = *(const half4v*)(msgB + (size_t)idx * LAT + o0);
    a0 += (float)ma.x; a1 += (float)ma.y; a2 += (float)ma.z; a3 += (float)ma.w;
    b0 += (float)mb.x; b1 += (float)mb.y; b2 += (float)mb.z; b3 += (float)mb.w;
  }
  float va0 = a0 + biasA[o0 + 0], va1 = a1 + biasA[o0 + 1];
  float va2 = a2 + biasA[o0 + 2], va3 = a3 + biasA[o0 + 3];
  float vb0 = b0 + biasB[o0 + 0], vb1 = b1 + biasB[o0 + 1];
  float vb2 = b2 + biasB[o0 + 2], vb3 = b3 + biasB[o0 + 3];
#pragma unroll
  for (int i = 0; i < DIN; i++) {
    const float xi = xin[(size_t)n * DIN + i];
    const float4 ra = *(const float4*)(rootA + (size_t)i * LAT + o0);
    const float4 rb = *(const float4*)(rootB + (size_t)i * LAT + o0);
    va0 = fmaf(xi, ra.x, va0); va1 = fmaf(xi, ra.y, va1);
    va2 = fmaf(xi, ra.z, va2); va3 = fmaf(xi, ra.w, va3);
    vb0 = fmaf(xi, rb.x, vb0); vb1 = fmaf(xi, rb.y, vb1);
    vb2 = fmaf(xi, rb.z, vb2); vb3 = fmaf(xi, rb.w, vb3);
  }
  *(float4*)(outA + (size_t)n * LAT + o0) = make_float4(va0, va1, va2, va3);
  *(float4*)(outB + (size_t)n * LAT + o0) = make_float4(vb0, vb1, vb2, vb3);
}

// ---------------------------------------------------------------------------
extern "C" void kernel_launch(void* const* d_in, const int* in_sizes, int n_in,
                              void* d_out, int out_size, void* d_ws, size_t ws_size,
                              hipStream_t stream) {
  const float* x  = (const float*)d_in[0];
  const int*   ei = (const int*)d_in[1];
  const float* ea = (const float*)d_in[2];
  const int* src = ei;
  const int* dst = ei + NE;

  auto P = [&](int c, int j) -> const float* {
    return (const float*)d_in[3 + c * 6 + j];
  };

  // workspace layout
  float* h1  = (float*)d_ws;                          // NN*HID f32
  float* h2  = h1 + (size_t)NN * HID;                 // NN*HID f32
  _Float16* msg = (_Float16*)(h2 + (size_t)NN * HID); // NE*32 fp16
  int* cnt    = (int*)(msg + (size_t)NE * 32);        // NN
  int* rowptr = cnt + NN;                             // NN+1 (pad 50004)
  int* wptr   = rowptr + 50004;                       // NN+1 (pad)
  int* epos   = wptr + 50004;                         // NE
  int* bsum   = epos + NE;                            // NSB (pad 256)
  _Float16* w2h_c1 = (_Float16*)(bsum + 256);           // HSTR*32*16
  _Float16* w2h_c2 = w2h_c1 + (size_t)HSTR * 32 * 16;   // HSTR*32*32
  _Float16* w2h_mu = w2h_c2 + (size_t)HSTR * 32 * 32;   // HSTR*16*32
  _Float16* w2h_lv = w2h_mu + (size_t)HSTR * 16 * 32;

  _Float16* msgA = msg;                    // dual: NE*16
  _Float16* msgB = msg + (size_t)NE * 16;

  float* out_mu = (float*)d_out;
  float* out_lv = out_mu + (size_t)NN * LAT;

  // ---- CSR build ----
  hipMemsetAsync(cnt, 0, (size_t)NN * sizeof(int), stream);
  count_kernel<<<dim3((NE + 255) / 256), dim3(256), 0, stream>>>(dst, cnt);
  scan1<<<dim3(NSB), dim3(SCB), 0, stream>>>(cnt, bsum);
  scan2<<<dim3(1), dim3(SCB), 0, stream>>>(bsum);
  scan3<<<dim3(NSB), dim3(SCB), 0, stream>>>(cnt, bsum, rowptr, wptr);
  fill_kernel<<<dim3((NE + 255) / 256), dim3(256), 0, stream>>>(dst, wptr, epos);

  // ---- weight swizzles ----
  {
    int t1 = HSTR * 16 * 32, t2 = HSTR * 32 * 32, t3 = HSTR * 32 * 16;
    swizzle_kernel<<<dim3((t1 + 255) / 256), dim3(256), 0, stream>>>(
        P(0, 2), P(0, 3), w2h_c1, IN, HID);
    swizzle_kernel<<<dim3((t2 + 255) / 256), dim3(256), 0, stream>>>(
        P(1, 2), P(1, 3), w2h_c2, HID, HID);
    swizzle_kernel<<<dim3((t3 + 255) / 256), dim3(256), 0, stream>>>(
        P(2, 2), P(2, 3), w2h_mu, HID, LAT);
    swizzle_kernel<<<dim3((t3 + 255) / 256), dim3(256), 0, stream>>>(
        P(3, 2), P(3, 3), w2h_lv, HID, LAT);
  }

  const dim3 egrid((NTILE + 3) / 4), eblk(128);   // 64 edges / block, 2 waves

  // conv1: 16 -> 32, mean, relu
  nnconv_mfma<IN, HID, false><<<egrid, eblk, 0, stream>>>(
      x, src, ea, P(0, 0), P(0, 1), nullptr, nullptr, w2h_c1, nullptr,
      epos, msg, nullptr);
  finish_kernel<IN, HID, true, true>
      <<<dim3((NN * (HID / 4) + 255) / 256), dim3(256), 0, stream>>>(
          msg, rowptr, x, P(0, 4), P(0, 5), h1);

  // conv2: 32 -> 32, mean, relu
  nnconv_mfma<HID, HID, false><<<egrid, eblk, 0, stream>>>(
      h1, src, ea, P(1, 0), P(1, 1), nullptr, nullptr, w2h_c2, nullptr,
      epos, msg, nullptr);
  finish_kernel<HID, HID, true, true>
      <<<dim3((NN * (HID / 4) + 255) / 256), dim3(256), 0, stream>>>(
          msg, rowptr, h1, P(1, 4), P(1, 5), h2);

  // cmu + clv fused (each with its OWN edge-MLP): 32 -> 16
  nnconv_mfma<HID, LAT, true><<<egrid, eblk, 0, stream>>>(
      h2, src, ea, P(2, 0), P(2, 1), P(3, 0), P(3, 1), w2h_mu, w2h_lv,
      epos, msgA, msgB);
  finish_dual<HID>
      <<<dim3((NN * (LAT / 4) + 255) / 256), dim3(256), 0, stream>>>(
          msgA, msgB, rowptr, h2, P(2, 4), P(2, 5), P(3, 4), P(3, 5),
          out_mu, out_lv);
}

// Round 9
// 362.332 us; speedup vs baseline: 10.2184x; 1.1070x over previous
//
#include <hip/hip_runtime.h>

typedef __attribute__((ext_vector_type(8))) _Float16 half8;
typedef __attribute__((ext_vector_type(4))) _Float16 half4v;
typedef __attribute__((ext_vector_type(2))) _Float16 half2v;
typedef __attribute__((ext_vector_type(4))) float f32x4;

constexpr int NN  = 50000;
constexpr int NE  = 150000;
constexpr int IN  = 16;
constexpr int HID = 32;
constexpr int LAT = 16;
constexpr int EF  = 8;
constexpr int HE  = 128;
constexpr int NTILE = NE / 16;      // 9375 (exact)
constexpr int HSTR  = HE + 2;       // weight-table kk rows (b2 at 128, 0 at 129)

constexpr int SCB = 256;
constexpr int NSB = (NN + SCB - 1) / SCB;   // 196

// A-fragment / h union
union XU {
  half2v h2[4];
  half8  h8;
  _Float16 h[8];
};

// ---------------------------------------------------------------------------
// CSR build (verified rounds 4-8)
// ---------------------------------------------------------------------------
__global__ void count_kernel(const int* __restrict__ dst, int* __restrict__ cnt) {
  int e = blockIdx.x * blockDim.x + threadIdx.x;
  if (e < NE) atomicAdd(&cnt[dst[e]], 1);
}

__launch_bounds__(SCB)
__global__ void scan1(const int* __restrict__ cnt, int* __restrict__ bsum) {
  __shared__ int sdata[SCB];
  const int i = blockIdx.x * SCB + threadIdx.x;
  sdata[threadIdx.x] = (i < NN) ? cnt[i] : 0;
  __syncthreads();
  for (int off = SCB / 2; off > 0; off >>= 1) {
    if (threadIdx.x < off) sdata[threadIdx.x] += sdata[threadIdx.x + off];
    __syncthreads();
  }
  if (threadIdx.x == 0) bsum[blockIdx.x] = sdata[0];
}

__launch_bounds__(SCB)
__global__ void scan2(int* __restrict__ bsum) {
  __shared__ int sdata[SCB];
  const int t = threadIdx.x;
  const int v = (t < NSB) ? bsum[t] : 0;
  sdata[t] = v;
  __syncthreads();
  for (int off = 1; off < SCB; off <<= 1) {
    int u = (t >= off) ? sdata[t - off] : 0;
    __syncthreads();
    sdata[t] += u;
    __syncthreads();
  }
  if (t < NSB) bsum[t] = sdata[t] - v;  // exclusive
}

__launch_bounds__(SCB)
__global__ void scan3(const int* __restrict__ cnt, const int* __restrict__ bsum,
                      int* __restrict__ rowptr, int* __restrict__ wptr) {
  __shared__ int sdata[SCB];
  const int i = blockIdx.x * SCB + threadIdx.x;
  const int t = threadIdx.x;
  const int v = (i < NN) ? cnt[i] : 0;
  sdata[t] = v;
  __syncthreads();
  for (int off = 1; off < SCB; off <<= 1) {
    int u = (t >= off) ? sdata[t - off] : 0;
    __syncthreads();
    sdata[t] += u;
    __syncthreads();
  }
  const int excl = sdata[t] - v + bsum[blockIdx.x];
  if (i < NN) {
    rowptr[i] = excl;
    wptr[i]   = excl;
  }
  if (i == NN - 1) rowptr[NN] = NE;
}

__global__ void fill_kernel(const int* __restrict__ dst, int* __restrict__ wptr,
                            int* __restrict__ epos) {
  int e = blockIdx.x * blockDim.x + threadIdx.x;
  if (e < NE) epos[e] = atomicAdd(&wptr[dst[e]], 1);
}

// ---------------------------------------------------------------------------
// Weight swizzle (verified round 5-8, byte-identical): fp32 w2[kk][i*DOUT+o]
// (+b2 at kk=HE, zeros at kk=HE+1) -> fp16 layout [kk][o][i], kk in [0, HSTR)
// ---------------------------------------------------------------------------
__global__ void swizzle_kernel(const float* __restrict__ w2, const float* __restrict__ b2,
                               _Float16* __restrict__ w2h, int DIN_, int DOUT_) {
  int idx = blockIdx.x * blockDim.x + threadIdx.x;
  int tot = HSTR * DIN_ * DOUT_;
  if (idx >= tot) return;
  int i  = idx % DIN_;
  int o  = (idx / DIN_) % DOUT_;
  int kk = idx / (DIN_ * DOUT_);
  float v = 0.0f;
  if (kk < HE)       v = w2[(size_t)kk * DIN_ * DOUT_ + i * DOUT_ + o];
  else if (kk == HE) v = b2[i * DOUT_ + o];
  w2h[idx] = (_Float16)v;
}

// ---------------------------------------------------------------------------
// MFMA edge kernel. Block = 128 thr = 2 waves; 4 A-tiles/wave = 128 edges.
// Phase 1: h = relu(ea@w1+b1) -> LDS fp16 [128][136] (136 = 16B-aligned rows,
//          2-way bank aliasing = free).
// Phase 2: 16 chunks x (8 kk); per chunk one ds_read_b128 of h per tile;
//          per step B-fragment load(s) feed 4 tiles (8 MFMA non-dual).
//          b2 epilogue: kk=128 step with h==1 (af = xv directly).
// DUAL (cmu+clv): two sequential passes, each with its OWN edge-MLP h.
// ---------------------------------------------------------------------------
template <int DIN, int DOUT, bool DUAL>
__launch_bounds__(128)
__global__ void nnconv_mfma(const float* __restrict__ xin,
                            const int*   __restrict__ src,
                            const float* __restrict__ ea,
                            const float* __restrict__ w1A,
                            const float* __restrict__ b1A,
                            const float* __restrict__ w1B,   // DUAL only
                            const float* __restrict__ b1B,   // DUAL only
                            const _Float16* __restrict__ w2hA, // [HSTR][DOUT][DIN]
                            const _Float16* __restrict__ w2hB, // DUAL only
                            const int*   __restrict__ epos,
                            _Float16* __restrict__ msgA,       // CSR-ordered fp16
                            _Float16* __restrict__ msgB)       // DUAL only
{
  constexpr int KKSTEP  = 32 / DIN;             // kk consumed per MFMA step
  constexpr int CHS     = 8 / KKSTEP;           // steps per 8-kk chunk (8 / 4)
  constexpr int BSTRIDE = KKSTEP * DOUT * DIN;  // elements per step
  constexpr int HS      = 136;                  // h LDS row stride (halves)
  constexpr int TILES   = 4;

  __shared__ float    ea_s[128 * EF];    // 4 KB
  __shared__ _Float16 h_s[128 * HS];     // 34 KB

  const int tid = threadIdx.x;
  const int eb  = blockIdx.x * 128;

  // ---- stage ea: thread tid = edge eb+tid, two float4 ----
  {
    const int e = eb + tid;
    float4 v0 = make_float4(0.f, 0.f, 0.f, 0.f), v1 = v0;
    if (e < NE) {
      const float4* p = (const float4*)(ea + (size_t)e * EF);
      v0 = p[0]; v1 = p[1];
    }
    float4* qp = (float4*)&ea_s[tid * EF];
    qp[0] = v0; qp[1] = v1;
  }
  __syncthreads();

  // ---- phase 1: h into LDS (thread = kk, 128 edges) ----
  auto build_h = [&](const float* __restrict__ w1, const float* __restrict__ b1) {
    const int kk = tid;
    float w1r[EF];
#pragma unroll
    for (int i = 0; i < EF; i++) w1r[i] = w1[i * HE + kk];
    const float bk = b1[kk];
#pragma unroll 4
    for (int e = 0; e < 128; e++) {
      const float4* p = (const float4*)&ea_s[e * EF];   // broadcast reads
      const float4 a = p[0], b = p[1];
      float hv = bk;
      hv = fmaf(a.x, w1r[0], hv); hv = fmaf(a.y, w1r[1], hv);
      hv = fmaf(a.z, w1r[2], hv); hv = fmaf(a.w, w1r[3], hv);
      hv = fmaf(b.x, w1r[4], hv); hv = fmaf(b.y, w1r[5], hv);
      hv = fmaf(b.z, w1r[6], hv); hv = fmaf(b.w, w1r[7], hv);
      hv = fmaxf(hv, 0.0f);
      h_s[e * HS + kk] = (_Float16)hv;
    }
  };

  build_h(w1A, b1A);
  __syncthreads();

  // ---- phase 2 common setup ----
  const int wave = tid >> 6;
  const int lane = tid & 63;
  const int m = lane & 15, q = lane >> 4;
  const int i0 = (q * 8) % DIN;
  const int kq = (q * 8) / DIN;          // 0 (DIN32) or 0/1 (DIN16)
  const int tg0 = blockIdx.x * 8 + wave * TILES;

  XU xv[TILES];
#pragma unroll
  for (int t = 0; t < TILES; t++) {
    const int tg = tg0 + t;
    if (tg < NTILE) {
      const int s = src[tg * 16 + m];
      const float4* xp = (const float4*)(xin + (size_t)s * DIN + i0);
      const float4 a = xp[0], b = xp[1];
      xv[t].h2[0] = (half2v){(_Float16)a.x, (_Float16)a.y};
      xv[t].h2[1] = (half2v){(_Float16)a.z, (_Float16)a.w};
      xv[t].h2[2] = (half2v){(_Float16)b.x, (_Float16)b.y};
      xv[t].h2[3] = (half2v){(_Float16)b.z, (_Float16)b.w};
    } else {
#pragma unroll
      for (int j = 0; j < 4; j++) xv[t].h2[j] = (half2v){(_Float16)0.f, (_Float16)0.f};
    }
  }

  f32x4 acc[TILES][2];
#pragma unroll
  for (int t = 0; t < TILES; t++)
#pragma unroll
    for (int f = 0; f < 2; f++) acc[t][f] = (f32x4){0.f, 0.f, 0.f, 0.f};

  int hrow[TILES];
#pragma unroll
  for (int t = 0; t < TILES; t++) hrow[t] = wave * 64 + t * 16 + m;

  // per-step A-fragment builder
  auto make_af = [&](const XU& xvt, _Float16 hv) -> XU {
    const half2v hb = (half2v){hv, hv};
    XU af;
#pragma unroll
    for (int j = 0; j < 4; j++) af.h2[j] = xvt.h2[j] * hb;   // v_pk_mul_f16
    return af;
  };

  if constexpr (DUAL) {
    // f-column filled per pass; h rebuilt between passes (separate edge-MLPs!)
    auto run_pass = [&](const _Float16* __restrict__ bp, const int f) {
#pragma unroll 1
      for (int c = 0; c < 16; c++) {
        XU hc[TILES];
#pragma unroll
        for (int t = 0; t < TILES; t++)
          hc[t].h8 = *(const half8*)&h_s[hrow[t] * HS + c * 8];
#pragma unroll
        for (int s = 0; s < CHS; s++) {
          const half8 bf = *(const half8*)(bp + (size_t)(c * CHS + s) * BSTRIDE);
#pragma unroll
          for (int t = 0; t < TILES; t++) {
            _Float16 hv;
            if (DIN == 32) hv = hc[t].h[s];
            else {
              const _Float16 h0 = hc[t].h[2 * s], h1 = hc[t].h[2 * s + 1];
              hv = kq ? h1 : h0;
            }
            const XU af = make_af(xv[t], hv);
            acc[t][f] = __builtin_amdgcn_mfma_f32_16x16x32_f16(af.h8, bf,
                                                               acc[t][f], 0, 0, 0);
          }
        }
      }
      // b2 epilogue: kk = 128, h == 1
      {
        const half8 bf = *(const half8*)(bp + (size_t)(128 / KKSTEP) * BSTRIDE);
#pragma unroll
        for (int t = 0; t < TILES; t++) {
          XU af;
          if (DIN == 32) af = xv[t];
          else {
#pragma unroll
            for (int j = 0; j < 4; j++)
              af.h2[j] = kq ? (half2v){(_Float16)0.f, (_Float16)0.f} : xv[t].h2[j];
          }
          acc[t][f] = __builtin_amdgcn_mfma_f32_16x16x32_f16(af.h8, bf,
                                                             acc[t][f], 0, 0, 0);
        }
      }
    };

    const _Float16* bpA = w2hA + (size_t)(kq * DOUT + m) * DIN + i0;
    const _Float16* bpB = w2hB + (size_t)(kq * DOUT + m) * DIN + i0;
    run_pass(bpA, 0);
    __syncthreads();              // all waves done reading h_mu
    build_h(w1B, b1B);
    __syncthreads();
    run_pass(bpB, 1);
  } else {
    // one h, two out-tiles sharing each A-fragment
    const _Float16* bp0 = w2hA + (size_t)(kq * DOUT + 0 + m) * DIN + i0;
    const _Float16* bp1 = w2hA + (size_t)(kq * DOUT + 16 + m) * DIN + i0;
#pragma unroll 1
    for (int c = 0; c < 16; c++) {
      XU hc[TILES];
#pragma unroll
      for (int t = 0; t < TILES; t++)
        hc[t].h8 = *(const half8*)&h_s[hrow[t] * HS + c * 8];
#pragma unroll
      for (int s = 0; s < CHS; s++) {
        const half8 bf0 = *(const half8*)(bp0 + (size_t)(c * CHS + s) * BSTRIDE);
        const half8 bf1 = *(const half8*)(bp1 + (size_t)(c * CHS + s) * BSTRIDE);
#pragma unroll
        for (int t = 0; t < TILES; t++) {
          _Float16 hv;
          if (DIN == 32) hv = hc[t].h[s];
          else {
            const _Float16 h0 = hc[t].h[2 * s], h1 = hc[t].h[2 * s + 1];
            hv = kq ? h1 : h0;
          }
          const XU af = make_af(xv[t], hv);
          acc[t][0] = __builtin_amdgcn_mfma_f32_16x16x32_f16(af.h8, bf0,
                                                             acc[t][0], 0, 0, 0);
          acc[t][1] = __builtin_amdgcn_mfma_f32_16x16x32_f16(af.h8, bf1,
                                                             acc[t][1], 0, 0, 0);
        }
      }
    }
    // b2 epilogue: kk = 128, h == 1
    {
      const half8 bf0 = *(const half8*)(bp0 + (size_t)(128 / KKSTEP) * BSTRIDE);
      const half8 bf1 = *(const half8*)(bp1 + (size_t)(128 / KKSTEP) * BSTRIDE);
#pragma unroll
      for (int t = 0; t < TILES; t++) {
        XU af;
        if (DIN == 32) af = xv[t];
        else {
#pragma unroll
          for (int j = 0; j < 4; j++)
            af.h2[j] = kq ? (half2v){(_Float16)0.f, (_Float16)0.f} : xv[t].h2[j];
        }
        acc[t][0] = __builtin_amdgcn_mfma_f32_16x16x32_f16(af.h8, bf0,
                                                           acc[t][0], 0, 0, 0);
        acc[t][1] = __builtin_amdgcn_mfma_f32_16x16x32_f16(af.h8, bf1,
                                                           acc[t][1], 0, 0, 0);
      }
    }
  }

  // ---- store msg (fp16) in CSR order: D row = q*4+r (edge), col = m ----
#pragma unroll
  for (int t = 0; t < TILES; t++) {
    const int tg = tg0 + t;
    if (tg < NTILE) {
      const int ebase = tg * 16 + q * 4;
      const int4 ep = *(const int4*)(epos + ebase);
      const int pr[4] = {ep.x, ep.y, ep.z, ep.w};
      if (DUAL) {
#pragma unroll
        for (int r = 0; r < 4; r++) {
          msgA[(size_t)pr[r] * DOUT + m] = (_Float16)acc[t][0][r];
          msgB[(size_t)pr[r] * DOUT + m] = (_Float16)acc[t][1][r];
        }
      } else {
#pragma unroll
        for (int f = 0; f < 2; f++)
#pragma unroll
          for (int r = 0; r < 4; r++)
            msgA[(size_t)pr[r] * DOUT + f * 16 + m] = (_Float16)acc[t][f][r];
      }
    }
  }
}

// ---------------------------------------------------------------------------
// Finish (single): out = (CSR-sum of fp16 msg) /deg? + x@root + bias, relu?
// ---------------------------------------------------------------------------
template <int DIN, int DOUT, bool MEAN, bool RELU>
__launch_bounds__(256)
__global__ void finish_kernel(const _Float16* __restrict__ msg,
                              const int* __restrict__ rowptr,
                              const float* __restrict__ xin,
                              const float* __restrict__ root,
                              const float* __restrict__ bias,
                              float* __restrict__ out) {
  constexpr int TPN = DOUT / 4;
  const int gid = blockIdx.x * 256 + threadIdx.x;
  const int n = gid / TPN, sub = gid % TPN;
  if (n >= NN) return;
  const int o0 = sub * 4;

  const int r0 = rowptr[n], r1 = rowptr[n + 1];
  float ax = 0.f, ay = 0.f, az = 0.f, aw = 0.f;
  for (int idx = r0; idx < r1; idx++) {
    const half4v mv = *(const half4v*)(msg + (size_t)idx * DOUT + o0);
    ax += (float)mv.x; ay += (float)mv.y; az += (float)mv.z; aw += (float)mv.w;
  }
  const float inv = MEAN ? 1.0f / fmaxf((float)(r1 - r0), 1.0f) : 1.0f;
  float vx = ax * inv + bias[o0 + 0];
  float vy = ay * inv + bias[o0 + 1];
  float vz = az * inv + bias[o0 + 2];
  float vw = aw * inv + bias[o0 + 3];
#pragma unroll
  for (int i = 0; i < DIN; i++) {
    const float xi = xin[(size_t)n * DIN + i];
    const float4 rv = *(const float4*)(root + (size_t)i * DOUT + o0);
    vx = fmaf(xi, rv.x, vx); vy = fmaf(xi, rv.y, vy);
    vz = fmaf(xi, rv.z, vz); vw = fmaf(xi, rv.w, vw);
  }
  if (RELU) {
    vx = fmaxf(vx, 0.f); vy = fmaxf(vy, 0.f);
    vz = fmaxf(vz, 0.f); vw = fmaxf(vw, 0.f);
  }
  *(float4*)(out + (size_t)n * DOUT + o0) = make_float4(vx, vy, vz, vw);
}

// Fused finish for mu+lv (DOUT=LAT=16, no mean, no relu)
template <int DIN>
__launch_bounds__(256)
__global__ void finish_dual(const _Float16* __restrict__ msgA,
                            const _Float16* __restrict__ msgB,
                            const int* __restrict__ rowptr,
                            const float* __restrict__ xin,
                            const float* __restrict__ rootA,
                            const float* __restrict__ biasA,
                            const float* __restrict__ rootB,
                            const float* __restrict__ biasB,
                            float* __restrict__ outA,
                            float* __restrict__ outB) {
  constexpr int TPN = LAT / 4;
  const int gid = blockIdx.x * 256 + threadIdx.x;
  const int n = gid / TPN, sub = gid % TPN;
  if (n >= NN) return;
  const int o0 = sub * 4;

  const int r0 = rowptr[n], r1 = rowptr[n + 1];
  float a0 = 0.f, a1 = 0.f, a2 = 0.f, a3 = 0.f;
  float b0 = 0.f, b1 = 0.f, b2 = 0.f, b3 = 0.f;
  for (int idx = r0; idx < r1; idx++) {
    const half4v ma = *(const half4v*)(msgA + (size_t)idx * LAT + o0);
    const half4v mb = *(const half4v*)(msgB + (size_t)idx * LAT + o0);
    a0 += (float)ma.x; a1 += (float)ma.y; a2 += (float)ma.z; a3 += (float)ma.w;
    b0 += (float)mb.x; b1 += (float)mb.y; b2 += (float)mb.z; b3 += (float)mb.w;
  }
  float va0 = a0 + biasA[o0 + 0], va1 = a1 + biasA[o0 + 1];
  float va2 = a2 + biasA[o0 + 2], va3 = a3 + biasA[o0 + 3];
  float vb0 = b0 + biasB[o0 + 0], vb1 = b1 + biasB[o0 + 1];
  float vb2 = b2 + biasB[o0 + 2], vb3 = b3 + biasB[o0 + 3];
#pragma unroll
  for (int i = 0; i < DIN; i++) {
    const float xi = xin[(size_t)n * DIN + i];
    const float4 ra = *(const float4*)(rootA + (size_t)i * LAT + o0);
    const float4 rb = *(const float4*)(rootB + (size_t)i * LAT + o0);
    va0 = fmaf(xi, ra.x, va0); va1 = fmaf(xi, ra.y, va1);
    va2 = fmaf(xi, ra.z, va2); va3 = fmaf(xi, ra.w, va3);
    vb0 = fmaf(xi, rb.x, vb0); vb1 = fmaf(xi, rb.y, vb1);
    vb2 = fmaf(xi, rb.z, vb2); vb3 = fmaf(xi, rb.w, vb3);
  }
  *(float4*)(outA + (size_t)n * LAT + o0) = make_float4(va0, va1, va2, va3);
  *(float4*)(outB + (size_t)n * LAT + o0) = make_float4(vb0, vb1, vb2, vb3);
}

// ---------------------------------------------------------------------------
extern "C" void kernel_launch(void* const* d_in, const int* in_sizes, int n_in,
                              void* d_out, int out_size, void* d_ws, size_t ws_size,
                              hipStream_t stream) {
  const float* x  = (const float*)d_in[0];
  const int*   ei = (const int*)d_in[1];
  const float* ea = (const float*)d_in[2];
  const int* src = ei;
  const int* dst = ei + NE;

  auto P = [&](int c, int j) -> const float* {
    return (const float*)d_in[3 + c * 6 + j];
  };

  // workspace layout
  float* h1  = (float*)d_ws;                          // NN*HID f32
  float* h2  = h1 + (size_t)NN * HID;                 // NN*HID f32
  _Float16* msg = (_Float16*)(h2 + (size_t)NN * HID); // NE*32 fp16
  int* cnt    = (int*)(msg + (size_t)NE * 32);        // NN
  int* rowptr = cnt + NN;                             // NN+1 (pad 50004)
  int* wptr   = rowptr + 50004;                       // NN+1 (pad)
  int* epos   = wptr + 50004;                         // NE
  int* bsum   = epos + NE;                            // NSB (pad 256)
  _Float16* w2h_c1 = (_Float16*)(bsum + 256);           // HSTR*32*16
  _Float16* w2h_c2 = w2h_c1 + (size_t)HSTR * 32 * 16;   // HSTR*32*32
  _Float16* w2h_mu = w2h_c2 + (size_t)HSTR * 32 * 32;   // HSTR*16*32
  _Float16* w2h_lv = w2h_mu + (size_t)HSTR * 16 * 32;

  _Float16* msgA = msg;                    // dual: NE*16
  _Float16* msgB = msg + (size_t)NE * 16;

  float* out_mu = (float*)d_out;
  float* out_lv = out_mu + (size_t)NN * LAT;

  // ---- CSR build ----
  hipMemsetAsync(cnt, 0, (size_t)NN * sizeof(int), stream);
  count_kernel<<<dim3((NE + 255) / 256), dim3(256), 0, stream>>>(dst, cnt);
  scan1<<<dim3(NSB), dim3(SCB), 0, stream>>>(cnt, bsum);
  scan2<<<dim3(1), dim3(SCB), 0, stream>>>(bsum);
  scan3<<<dim3(NSB), dim3(SCB), 0, stream>>>(cnt, bsum, rowptr, wptr);
  fill_kernel<<<dim3((NE + 255) / 256), dim3(256), 0, stream>>>(dst, wptr, epos);

  // ---- weight swizzles ----
  {
    int t1 = HSTR * 16 * 32, t2 = HSTR * 32 * 32, t3 = HSTR * 32 * 16;
    swizzle_kernel<<<dim3((t1 + 255) / 256), dim3(256), 0, stream>>>(
        P(0, 2), P(0, 3), w2h_c1, IN, HID);
    swizzle_kernel<<<dim3((t2 + 255) / 256), dim3(256), 0, stream>>>(
        P(1, 2), P(1, 3), w2h_c2, HID, HID);
    swizzle_kernel<<<dim3((t3 + 255) / 256), dim3(256), 0, stream>>>(
        P(2, 2), P(2, 3), w2h_mu, HID, LAT);
    swizzle_kernel<<<dim3((t3 + 255) / 256), dim3(256), 0, stream>>>(
        P(3, 2), P(3, 3), w2h_lv, HID, LAT);
  }

  const dim3 egrid((NTILE + 7) / 8), eblk(128);   // 128 edges / block, 2 waves

  // conv1: 16 -> 32, mean, relu
  nnconv_mfma<IN, HID, false><<<egrid, eblk, 0, stream>>>(
      x, src, ea, P(0, 0), P(0, 1), nullptr, nullptr, w2h_c1, nullptr,
      epos, msg, nullptr);
  finish_kernel<IN, HID, true, true>
      <<<dim3((NN * (HID / 4) + 255) / 256), dim3(256), 0, stream>>>(
          msg, rowptr, x, P(0, 4), P(0, 5), h1);

  // conv2: 32 -> 32, mean, relu
  nnconv_mfma<HID, HID, false><<<egrid, eblk, 0, stream>>>(
      h1, src, ea, P(1, 0), P(1, 1), nullptr, nullptr, w2h_c2, nullptr,
      epos, msg, nullptr);
  finish_kernel<HID, HID, true, true>
      <<<dim3((NN * (HID / 4) + 255) / 256), dim3(256), 0, stream>>>(
          msg, rowptr, h1, P(1, 4), P(1, 5), h2);

  // cmu + clv fused (each with its OWN edge-MLP): 32 -> 16
  nnconv_mfma<HID, LAT, true><<<egrid, eblk, 0, stream>>>(
      h2, src, ea, P(2, 0), P(2, 1), P(3, 0), P(3, 1), w2h_mu, w2h_lv,
      epos, msgA, msgB);
  finish_dual<HID>
      <<<dim3((NN * (LAT / 4) + 255) / 256), dim3(256), 0, stream>>>(
          msgA, msgB, rowptr, h2, P(2, 4), P(2, 5), P(3, 4), P(3, 5),
          out_mu, out_lv);
}

// Round 10
// 361.552 us; speedup vs baseline: 10.2404x; 1.0022x over previous
//
#include <hip/hip_runtime.h>

typedef __attribute__((ext_vector_type(8))) _Float16 half8;
typedef __attribute__((ext_vector_type(4))) _Float16 half4v;
typedef __attribute__((ext_vector_type(2))) _Float16 half2v;
typedef __attribute__((ext_vector_type(4))) float f32x4;

constexpr int NN  = 50000;
constexpr int NE  = 150000;
constexpr int IN  = 16;
constexpr int HID = 32;
constexpr int LAT = 16;
constexpr int EF  = 8;
constexpr int HE  = 128;
constexpr int NTILE = NE / 16;      // 9375 (exact)
constexpr int HSTR  = HE + 2;       // weight-table kk rows (b2 at 128, 0 at 129)

constexpr int SCB = 256;
constexpr int NSB = (NN + SCB - 1) / SCB;   // 196

// A-fragment / h union
union XU {
  half2v h2[4];
  half8  h8;
  _Float16 h[8];
};

// ---------------------------------------------------------------------------
// CSR build (verified rounds 4-9)
// ---------------------------------------------------------------------------
__global__ void count_kernel(const int* __restrict__ dst, int* __restrict__ cnt) {
  int e = blockIdx.x * blockDim.x + threadIdx.x;
  if (e < NE) atomicAdd(&cnt[dst[e]], 1);
}

__launch_bounds__(SCB)
__global__ void scan1(const int* __restrict__ cnt, int* __restrict__ bsum) {
  __shared__ int sdata[SCB];
  const int i = blockIdx.x * SCB + threadIdx.x;
  sdata[threadIdx.x] = (i < NN) ? cnt[i] : 0;
  __syncthreads();
  for (int off = SCB / 2; off > 0; off >>= 1) {
    if (threadIdx.x < off) sdata[threadIdx.x] += sdata[threadIdx.x + off];
    __syncthreads();
  }
  if (threadIdx.x == 0) bsum[blockIdx.x] = sdata[0];
}

__launch_bounds__(SCB)
__global__ void scan2(int* __restrict__ bsum) {
  __shared__ int sdata[SCB];
  const int t = threadIdx.x;
  const int v = (t < NSB) ? bsum[t] : 0;
  sdata[t] = v;
  __syncthreads();
  for (int off = 1; off < SCB; off <<= 1) {
    int u = (t >= off) ? sdata[t - off] : 0;
    __syncthreads();
    sdata[t] += u;
    __syncthreads();
  }
  if (t < NSB) bsum[t] = sdata[t] - v;  // exclusive
}

__launch_bounds__(SCB)
__global__ void scan3(const int* __restrict__ cnt, const int* __restrict__ bsum,
                      int* __restrict__ rowptr, int* __restrict__ wptr) {
  __shared__ int sdata[SCB];
  const int i = blockIdx.x * SCB + threadIdx.x;
  const int t = threadIdx.x;
  const int v = (i < NN) ? cnt[i] : 0;
  sdata[t] = v;
  __syncthreads();
  for (int off = 1; off < SCB; off <<= 1) {
    int u = (t >= off) ? sdata[t - off] : 0;
    __syncthreads();
    sdata[t] += u;
    __syncthreads();
  }
  const int excl = sdata[t] - v + bsum[blockIdx.x];
  if (i < NN) {
    rowptr[i] = excl;
    wptr[i]   = excl;
  }
  if (i == NN - 1) rowptr[NN] = NE;
}

__global__ void fill_kernel(const int* __restrict__ dst, int* __restrict__ wptr,
                            int* __restrict__ epos) {
  int e = blockIdx.x * blockDim.x + threadIdx.x;
  if (e < NE) epos[e] = atomicAdd(&wptr[dst[e]], 1);
}

// ---------------------------------------------------------------------------
// Weight prep: (a) w2 fp32 [kk][i*DOUT+o] (+b2 at kk=HE, zeros at kk=HE+1)
//   -> fp16 layout [kk][o][i], kk in [0, HSTR)   [verified rounds 5-9]
// (b) NEW: w1 [i][kk] -> w1t [kk][i] fp32 (for wave-uniform s_load in build_h)
// ---------------------------------------------------------------------------
__global__ void swizzle_kernel(const float* __restrict__ w2, const float* __restrict__ b2,
                               const float* __restrict__ w1,
                               _Float16* __restrict__ w2h, float* __restrict__ w1t,
                               int DIN_, int DOUT_) {
  int idx = blockIdx.x * blockDim.x + threadIdx.x;
  if (idx < HE * EF) {                 // w1t[kk][i] = w1[i][kk]
    int kk = idx / EF, i = idx % EF;
    w1t[idx] = w1[i * HE + kk];
  }
  int tot = HSTR * DIN_ * DOUT_;
  if (idx >= tot) return;
  int i  = idx % DIN_;
  int o  = (idx / DIN_) % DOUT_;
  int kk = idx / (DIN_ * DOUT_);
  float v = 0.0f;
  if (kk < HE)       v = w2[(size_t)kk * DIN_ * DOUT_ + i * DOUT_ + o];
  else if (kk == HE) v = b2[i * DOUT_ + o];
  w2h[idx] = (_Float16)v;
}

// ---------------------------------------------------------------------------
// MFMA edge kernel. Block = 128 thr = 2 waves; 4 A-tiles/wave = 128 edges.
// Phase 1 (NEW): thread = edge; ea lives in 8 VGPRs (global->reg, no LDS);
//   w1t/b1 read as wave-uniform s_loads; 8 kk packed per ds_write_b128.
// Phase 2 (verified round 9, byte-identical): 16 chunks x 8 kk; one
//   ds_read_b128 of h per tile per chunk; B-fragment loads feed 4 tiles;
//   b2 epilogue step with h==1.
// DUAL (cmu+clv): two sequential passes, each with its OWN edge-MLP h.
// ---------------------------------------------------------------------------
template <int DIN, int DOUT, bool DUAL>
__launch_bounds__(128)
__global__ void nnconv_mfma(const float* __restrict__ xin,
                            const int*   __restrict__ src,
                            const float* __restrict__ ea,
                            const float* __restrict__ w1tA,  // [HE][EF] fp32
                            const float* __restrict__ b1A,
                            const float* __restrict__ w1tB,  // DUAL only
                            const float* __restrict__ b1B,   // DUAL only
                            const _Float16* __restrict__ w2hA, // [HSTR][DOUT][DIN]
                            const _Float16* __restrict__ w2hB, // DUAL only
                            const int*   __restrict__ epos,
                            _Float16* __restrict__ msgA,       // CSR-ordered fp16
                            _Float16* __restrict__ msgB)       // DUAL only
{
  constexpr int KKSTEP  = 32 / DIN;             // kk consumed per MFMA step
  constexpr int CHS     = 8 / KKSTEP;           // steps per 8-kk chunk (8 / 4)
  constexpr int BSTRIDE = KKSTEP * DOUT * DIN;  // elements per step
  constexpr int HS      = 136;                  // h LDS row stride (halves)
  constexpr int TILES   = 4;

  __shared__ _Float16 h_s[128 * HS];     // 34.8 KB (no ea_s anymore)

  const int tid = threadIdx.x;
  const int eb  = blockIdx.x * 128;

  // ---- ea straight into registers (thread = edge) ----
  float eav[EF];
  {
    const int e = eb + tid;
    float4 v0 = make_float4(0.f, 0.f, 0.f, 0.f), v1 = v0;
    if (e < NE) {
      const float4* p = (const float4*)(ea + (size_t)e * EF);
      v0 = p[0]; v1 = p[1];
    }
    eav[0] = v0.x; eav[1] = v0.y; eav[2] = v0.z; eav[3] = v0.w;
    eav[4] = v1.x; eav[5] = v1.y; eav[6] = v1.z; eav[7] = v1.w;
  }

  // ---- phase 1: h for own edge, all 128 kk; w1t/b1 are uniform s_loads ----
  auto build_h = [&](const float* __restrict__ w1t, const float* __restrict__ b1) {
#pragma unroll 1
    for (int c = 0; c < 16; c++) {
      const float4 bq0 = *(const float4*)&b1[c * 8];
      const float4 bq1 = *(const float4*)&b1[c * 8 + 4];
      const float bk[8] = {bq0.x, bq0.y, bq0.z, bq0.w, bq1.x, bq1.y, bq1.z, bq1.w};
      XU hr;
#pragma unroll
      for (int j = 0; j < 8; j++) {
        const int kk = c * 8 + j;
        const float4 wa = *(const float4*)&w1t[kk * EF];
        const float4 wb = *(const float4*)&w1t[kk * EF + 4];
        float hv = bk[j];
        hv = fmaf(eav[0], wa.x, hv); hv = fmaf(eav[1], wa.y, hv);
        hv = fmaf(eav[2], wa.z, hv); hv = fmaf(eav[3], wa.w, hv);
        hv = fmaf(eav[4], wb.x, hv); hv = fmaf(eav[5], wb.y, hv);
        hv = fmaf(eav[6], wb.z, hv); hv = fmaf(eav[7], wb.w, hv);
        hv = fmaxf(hv, 0.0f);
        hr.h[j] = (_Float16)hv;
      }
      *(half8*)&h_s[tid * HS + c * 8] = hr.h8;
    }
  };

  build_h(w1tA, b1A);
  __syncthreads();

  // ---- phase 2 common setup (verified round 9) ----
  const int wave = tid >> 6;
  const int lane = tid & 63;
  const int m = lane & 15, q = lane >> 4;
  const int i0 = (q * 8) % DIN;
  const int kq = (q * 8) / DIN;          // 0 (DIN32) or 0/1 (DIN16)
  const int tg0 = blockIdx.x * 8 + wave * TILES;

  XU xv[TILES];
#pragma unroll
  for (int t = 0; t < TILES; t++) {
    const int tg = tg0 + t;
    if (tg < NTILE) {
      const int s = src[tg * 16 + m];
      const float4* xp = (const float4*)(xin + (size_t)s * DIN + i0);
      const float4 a = xp[0], b = xp[1];
      xv[t].h2[0] = (half2v){(_Float16)a.x, (_Float16)a.y};
      xv[t].h2[1] = (half2v){(_Float16)a.z, (_Float16)a.w};
      xv[t].h2[2] = (half2v){(_Float16)b.x, (_Float16)b.y};
      xv[t].h2[3] = (half2v){(_Float16)b.z, (_Float16)b.w};
    } else {
#pragma unroll
      for (int j = 0; j < 4; j++) xv[t].h2[j] = (half2v){(_Float16)0.f, (_Float16)0.f};
    }
  }

  f32x4 acc[TILES][2];
#pragma unroll
  for (int t = 0; t < TILES; t++)
#pragma unroll
    for (int f = 0; f < 2; f++) acc[t][f] = (f32x4){0.f, 0.f, 0.f, 0.f};

  int hrow[TILES];
#pragma unroll
  for (int t = 0; t < TILES; t++) hrow[t] = wave * 64 + t * 16 + m;

  auto make_af = [&](const XU& xvt, _Float16 hv) -> XU {
    const half2v hb = (half2v){hv, hv};
    XU af;
#pragma unroll
    for (int j = 0; j < 4; j++) af.h2[j] = xvt.h2[j] * hb;   // v_pk_mul_f16
    return af;
  };

  if constexpr (DUAL) {
    auto run_pass = [&](const _Float16* __restrict__ bp, const int f) {
#pragma unroll 1
      for (int c = 0; c < 16; c++) {
        XU hc[TILES];
#pragma unroll
        for (int t = 0; t < TILES; t++)
          hc[t].h8 = *(const half8*)&h_s[hrow[t] * HS + c * 8];
#pragma unroll
        for (int s = 0; s < CHS; s++) {
          const half8 bf = *(const half8*)(bp + (size_t)(c * CHS + s) * BSTRIDE);
#pragma unroll
          for (int t = 0; t < TILES; t++) {
            _Float16 hv;
            if (DIN == 32) hv = hc[t].h[s];
            else {
              const _Float16 h0 = hc[t].h[2 * s], h1 = hc[t].h[2 * s + 1];
              hv = kq ? h1 : h0;
            }
            const XU af = make_af(xv[t], hv);
            acc[t][f] = __builtin_amdgcn_mfma_f32_16x16x32_f16(af.h8, bf,
                                                               acc[t][f], 0, 0, 0);
          }
        }
      }
      // b2 epilogue: kk = 128, h == 1
      {
        const half8 bf = *(const half8*)(bp + (size_t)(128 / KKSTEP) * BSTRIDE);
#pragma unroll
        for (int t = 0; t < TILES; t++) {
          XU af;
          if (DIN == 32) af = xv[t];
          else {
#pragma unroll
            for (int j = 0; j < 4; j++)
              af.h2[j] = kq ? (half2v){(_Float16)0.f, (_Float16)0.f} : xv[t].h2[j];
          }
          acc[t][f] = __builtin_amdgcn_mfma_f32_16x16x32_f16(af.h8, bf,
                                                             acc[t][f], 0, 0, 0);
        }
      }
    };

    const _Float16* bpA = w2hA + (size_t)(kq * DOUT + m) * DIN + i0;
    const _Float16* bpB = w2hB + (size_t)(kq * DOUT + m) * DIN + i0;
    run_pass(bpA, 0);
    __syncthreads();              // all waves done reading h_mu
    build_h(w1tB, b1B);
    __syncthreads();
    run_pass(bpB, 1);
  } else {
    const _Float16* bp0 = w2hA + (size_t)(kq * DOUT + 0 + m) * DIN + i0;
    const _Float16* bp1 = w2hA + (size_t)(kq * DOUT + 16 + m) * DIN + i0;
#pragma unroll 1
    for (int c = 0; c < 16; c++) {
      XU hc[TILES];
#pragma unroll
      for (int t = 0; t < TILES; t++)
        hc[t].h8 = *(const half8*)&h_s[hrow[t] * HS + c * 8];
#pragma unroll
      for (int s = 0; s < CHS; s++) {
        const half8 bf0 = *(const half8*)(bp0 + (size_t)(c * CHS + s) * BSTRIDE);
        const half8 bf1 = *(const half8*)(bp1 + (size_t)(c * CHS + s) * BSTRIDE);
#pragma unroll
        for (int t = 0; t < TILES; t++) {
          _Float16 hv;
          if (DIN == 32) hv = hc[t].h[s];
          else {
            const _Float16 h0 = hc[t].h[2 * s], h1 = hc[t].h[2 * s + 1];
            hv = kq ? h1 : h0;
          }
          const XU af = make_af(xv[t], hv);
          acc[t][0] = __builtin_amdgcn_mfma_f32_16x16x32_f16(af.h8, bf0,
                                                             acc[t][0], 0, 0, 0);
          acc[t][1] = __builtin_amdgcn_mfma_f32_16x16x32_f16(af.h8, bf1,
                                                             acc[t][1], 0, 0, 0);
        }
      }
    }
    // b2 epilogue: kk = 128, h == 1
    {
      const half8 bf0 = *(const half8*)(bp0 + (size_t)(128 / KKSTEP) * BSTRIDE);
      const half8 bf1 = *(const half8*)(bp1 + (size_t)(128 / KKSTEP) * BSTRIDE);
#pragma unroll
      for (int t = 0; t < TILES; t++) {
        XU af;
        if (DIN == 32) af = xv[t];
        else {
#pragma unroll
          for (int j = 0; j < 4; j++)
            af.h2[j] = kq ? (half2v){(_Float16)0.f, (_Float16)0.f} : xv[t].h2[j];
        }
        acc[t][0] = __builtin_amdgcn_mfma_f32_16x16x32_f16(af.h8, bf0,
                                                           acc[t][0], 0, 0, 0);
        acc[t][1] = __builtin_amdgcn_mfma_f32_16x16x32_f16(af.h8, bf1,
                                                           acc[t][1], 0, 0, 0);
      }
    }
  }

  // ---- store msg (fp16) in CSR order: D row = q*4+r (edge), col = m ----
#pragma unroll
  for (int t = 0; t < TILES; t++) {
    const int tg = tg0 + t;
    if (tg < NTILE) {
      const int ebase = tg * 16 + q * 4;
      const int4 ep = *(const int4*)(epos + ebase);
      const int pr[4] = {ep.x, ep.y, ep.z, ep.w};
      if (DUAL) {
#pragma unroll
        for (int r = 0; r < 4; r++) {
          msgA[(size_t)pr[r] * DOUT + m] = (_Float16)acc[t][0][r];
          msgB[(size_t)pr[r] * DOUT + m] = (_Float16)acc[t][1][r];
        }
      } else {
#pragma unroll
        for (int f = 0; f < 2; f++)
#pragma unroll
          for (int r = 0; r < 4; r++)
            msgA[(size_t)pr[r] * DOUT + f * 16 + m] = (_Float16)acc[t][f][r];
      }
    }
  }
}

// ---------------------------------------------------------------------------
// Finish (single): out = (CSR-sum of fp16 msg) /deg? + x@root + bias, relu?
// ---------------------------------------------------------------------------
template <int DIN, int DOUT, bool MEAN, bool RELU>
__launch_bounds__(256)
__global__ void finish_kernel(const _Float16* __restrict__ msg,
                              const int* __restrict__ rowptr,
                              const float* __restrict__ xin,
                              const float* __restrict__ root,
                              const float* __restrict__ bias,
                              float* __restrict__ out) {
  constexpr int TPN = DOUT / 4;
  const int gid = blockIdx.x * 256 + threadIdx.x;
  const int n = gid / TPN, sub = gid % TPN;
  if (n >= NN) return;
  const int o0 = sub * 4;

  const int r0 = rowptr[n], r1 = rowptr[n + 1];
  float ax = 0.f, ay = 0.f, az = 0.f, aw = 0.f;
  for (int idx = r0; idx < r1; idx++) {
    const half4v mv = *(const half4v*)(msg + (size_t)idx * DOUT + o0);
    ax += (float)mv.x; ay += (float)mv.y; az += (float)mv.z; aw += (float)mv.w;
  }
  const float inv = MEAN ? 1.0f / fmaxf((float)(r1 - r0), 1.0f) : 1.0f;
  float vx = ax * inv + bias[o0 + 0];
  float vy = ay * inv + bias[o0 + 1];
  float vz = az * inv + bias[o0 + 2];
  float vw = aw * inv + bias[o0 + 3];
#pragma unroll
  for (int i = 0; i < DIN; i++) {
    const float xi = xin[(size_t)n * DIN + i];
    const float4 rv = *(const float4*)(root + (size_t)i * DOUT + o0);
    vx = fmaf(xi, rv.x, vx); vy = fmaf(xi, rv.y, vy);
    vz = fmaf(xi, rv.z, vz); vw = fmaf(xi, rv.w, vw);
  }
  if (RELU) {
    vx = fmaxf(vx, 0.f); vy = fmaxf(vy, 0.f);
    vz = fmaxf(vz, 0.f); vw = fmaxf(vw, 0.f);
  }
  *(float4*)(out + (size_t)n * DOUT + o0) = make_float4(vx, vy, vz, vw);
}

// Fused finish for mu+lv (DOUT=LAT=16, no mean, no relu)
template <int DIN>
__launch_bounds__(256)
__global__ void finish_dual(const _Float16* __restrict__ msgA,
                            const _Float16* __restrict__ msgB,
                            const int* __restrict__ rowptr,
                            const float* __restrict__ xin,
                            const float* __restrict__ rootA,
                            const float* __restrict__ biasA,
                            const float* __restrict__ rootB,
                            const float* __restrict__ biasB,
                            float* __restrict__ outA,
                            float* __restrict__ outB) {
  constexpr int TPN = LAT / 4;
  const int gid = blockIdx.x * 256 + threadIdx.x;
  const int n = gid / TPN, sub = gid % TPN;
  if (n >= NN) return;
  const int o0 = sub * 4;

  const int r0 = rowptr[n], r1 = rowptr[n + 1];
  float a0 = 0.f, a1 = 0.f, a2 = 0.f, a3 = 0.f;
  float b0 = 0.f, b1 = 0.f, b2 = 0.f, b3 = 0.f;
  for (int idx = r0; idx < r1; idx++) {
    const half4v ma = *(const half4v*)(msgA + (size_t)idx * LAT + o0);
    const half4v mb = *(const half4v*)(msgB + (size_t)idx * LAT + o0);
    a0 += (float)ma.x; a1 += (float)ma.y; a2 += (float)ma.z; a3 += (float)ma.w;
    b0 += (float)mb.x; b1 += (float)mb.y; b2 += (float)mb.z; b3 += (float)mb.w;
  }
  float va0 = a0 + biasA[o0 + 0], va1 = a1 + biasA[o0 + 1];
  float va2 = a2 + biasA[o0 + 2], va3 = a3 + biasA[o0 + 3];
  float vb0 = b0 + biasB[o0 + 0], vb1 = b1 + biasB[o0 + 1];
  float vb2 = b2 + biasB[o0 + 2], vb3 = b3 + biasB[o0 + 3];
#pragma unroll
  for (int i = 0; i < DIN; i++) {
    const float xi = xin[(size_t)n * DIN + i];
    const float4 ra = *(const float4*)(rootA + (size_t)i * LAT + o0);
    const float4 rb = *(const float4*)(rootB + (size_t)i * LAT + o0);
    va0 = fmaf(xi, ra.x, va0); va1 = fmaf(xi, ra.y, va1);
    va2 = fmaf(xi, ra.z, va2); va3 = fmaf(xi, ra.w, va3);
    vb0 = fmaf(xi, rb.x, vb0); vb1 = fmaf(xi, rb.y, vb1);
    vb2 = fmaf(xi, rb.z, vb2); vb3 = fmaf(xi, rb.w, vb3);
  }
  *(float4*)(outA + (size_t)n * LAT + o0) = make_float4(va0, va1, va2, va3);
  *(float4*)(outB + (size_t)n * LAT + o0) = make_float4(vb0, vb1, vb2, vb3);
}

// ---------------------------------------------------------------------------
extern "C" void kernel_launch(void* const* d_in, const int* in_sizes, int n_in,
                              void* d_out, int out_size, void* d_ws, size_t ws_size,
                              hipStream_t stream) {
  const float* x  = (const float*)d_in[0];
  const int*   ei = (const int*)d_in[1];
  const float* ea = (const float*)d_in[2];
  const int* src = ei;
  const int* dst = ei + NE;

  auto P = [&](int c, int j) -> const float* {
    return (const float*)d_in[3 + c * 6 + j];
  };

  // workspace layout
  float* h1  = (float*)d_ws;                          // NN*HID f32
  float* h2  = h1 + (size_t)NN * HID;                 // NN*HID f32
  _Float16* msg = (_Float16*)(h2 + (size_t)NN * HID); // NE*32 fp16
  int* cnt    = (int*)(msg + (size_t)NE * 32);        // NN
  int* rowptr = cnt + NN;                             // NN+1 (pad 50004)
  int* wptr   = rowptr + 50004;                       // NN+1 (pad)
  int* epos   = wptr + 50004;                         // NE
  int* bsum   = epos + NE;                            // NSB (pad 256)
  _Float16* w2h_c1 = (_Float16*)(bsum + 256);           // HSTR*32*16
  _Float16* w2h_c2 = w2h_c1 + (size_t)HSTR * 32 * 16;   // HSTR*32*32
  _Float16* w2h_mu = w2h_c2 + (size_t)HSTR * 32 * 32;   // HSTR*16*32
  _Float16* w2h_lv = w2h_mu + (size_t)HSTR * 16 * 32;
  float* w1t_c1 = (float*)(w2h_lv + (size_t)HSTR * 16 * 32);  // HE*EF each
  float* w1t_c2 = w1t_c1 + HE * EF;
  float* w1t_mu = w1t_c2 + HE * EF;
  float* w1t_lv = w1t_mu + HE * EF;

  _Float16* msgA = msg;                    // dual: NE*16
  _Float16* msgB = msg + (size_t)NE * 16;

  float* out_mu = (float*)d_out;
  float* out_lv = out_mu + (size_t)NN * LAT;

  // ---- CSR build ----
  hipMemsetAsync(cnt, 0, (size_t)NN * sizeof(int), stream);
  count_kernel<<<dim3((NE + 255) / 256), dim3(256), 0, stream>>>(dst, cnt);
  scan1<<<dim3(NSB), dim3(SCB), 0, stream>>>(cnt, bsum);
  scan2<<<dim3(1), dim3(SCB), 0, stream>>>(bsum);
  scan3<<<dim3(NSB), dim3(SCB), 0, stream>>>(cnt, bsum, rowptr, wptr);
  fill_kernel<<<dim3((NE + 255) / 256), dim3(256), 0, stream>>>(dst, wptr, epos);

  // ---- weight prep (w2 swizzle + w1 transpose) ----
  {
    int t1 = HSTR * 16 * 32, t2 = HSTR * 32 * 32, t3 = HSTR * 32 * 16;
    swizzle_kernel<<<dim3((t1 + 255) / 256), dim3(256), 0, stream>>>(
        P(0, 2), P(0, 3), P(0, 0), w2h_c1, w1t_c1, IN, HID);
    swizzle_kernel<<<dim3((t2 + 255) / 256), dim3(256), 0, stream>>>(
        P(1, 2), P(1, 3), P(1, 0), w2h_c2, w1t_c2, HID, HID);
    swizzle_kernel<<<dim3((t3 + 255) / 256), dim3(256), 0, stream>>>(
        P(2, 2), P(2, 3), P(2, 0), w2h_mu, w1t_mu, HID, LAT);
    swizzle_kernel<<<dim3((t3 + 255) / 256), dim3(256), 0, stream>>>(
        P(3, 2), P(3, 3), P(3, 0), w2h_lv, w1t_lv, HID, LAT);
  }

  const dim3 egrid((NTILE + 7) / 8), eblk(128);   // 128 edges / block, 2 waves

  // conv1: 16 -> 32, mean, relu
  nnconv_mfma<IN, HID, false><<<egrid, eblk, 0, stream>>>(
      x, src, ea, w1t_c1, P(0, 1), nullptr, nullptr, w2h_c1, nullptr,
      epos, msg, nullptr);
  finish_kernel<IN, HID, true, true>
      <<<dim3((NN * (HID / 4) + 255) / 256), dim3(256), 0, stream>>>(
          msg, rowptr, x, P(0, 4), P(0, 5), h1);

  // conv2: 32 -> 32, mean, relu
  nnconv_mfma<HID, HID, false><<<egrid, eblk, 0, stream>>>(
      h1, src, ea, w1t_c2, P(1, 1), nullptr, nullptr, w2h_c2, nullptr,
      epos, msg, nullptr);
  finish_kernel<HID, HID, true, true>
      <<<dim3((NN * (HID / 4) + 255) / 256), dim3(256), 0, stream>>>(
          msg, rowptr, h1, P(1, 4), P(1, 5), h2);

  // cmu + clv fused (each with its OWN edge-MLP): 32 -> 16
  nnconv_mfma<HID, LAT, true><<<egrid, eblk, 0, stream>>>(
      h2, src, ea, w1t_mu, P(2, 1), w1t_lv, P(3, 1), w2h_mu, w2h_lv,
      epos, msgA, msgB);
  finish_dual<HID>
      <<<dim3((NN * (LAT / 4) + 255) / 256), dim3(256), 0, stream>>>(
          msgA, msgB, rowptr, h2, P(2, 4), P(2, 5), P(3, 4), P(3, 5),
          out_mu, out_lv);
}